// Round 11
// baseline (534.317 us; speedup 1.0000x reference)
//
#include <hip/hip_runtime.h>

#define NN 50000
#define DD 128
#define EE 800000
#define THRV 0.3f
#define SCAN_BLK 25           // ceil(50000 / 2048)
#define NB 196                // ceil(50000 / 256) dst-buckets of 256 nodes
#define BCAP 5120             // bucket capacity; mean 4096, sigma ~64 -> 16 sigma

typedef unsigned short u16;
typedef _Float16 f16x8 __attribute__((ext_vector_type(8)));
typedef float    f32x4 __attribute__((ext_vector_type(4)));

__device__ __forceinline__ float bf2f(u16 u){
    union { unsigned int i; float f; } v; v.i = ((unsigned int)u) << 16; return v.f;
}
__device__ __forceinline__ u16 f2bf(float f){
    unsigned int x = __float_as_uint(f);
    unsigned int r = (x + 0x7fffu + ((x >> 16) & 1u)) >> 16;
    return (u16)r;
}
__device__ __forceinline__ u16 f2h(float f){
    union { _Float16 h; u16 u; } v; v.h = (_Float16)f; return v.u;
}
__device__ __forceinline__ float h2f(u16 u){
    union { _Float16 h; u16 u; } v; v.u = u; return (float)v.h;
}

// ---------------------------------------------------------------------------
// K0: zero degree counters + bucket cursors (contiguous in workspace)
// ---------------------------------------------------------------------------
__global__ __launch_bounds__(256)
void k_zero(int* p, int n)
{
    int i = blockIdx.x * 256 + threadIdx.x;
    if (i < n) p[i] = 0;
}

// ---------------------------------------------------------------------------
// K1: boundary MLP via MFMA.  b = sigmoid(relu(relu(x@W1+b1)@W2+b2)@W3+b3)
// (round-9 verified: 85us fp32 -> out of top-5; absmax unchanged)
// m89 layouts: A: lane l = A[l&15][(l>>4)*8..+7]; B: lane l = B[(l>>4)*8..+7][l&15]
// (W staged TRANSPOSED); C/D: col=lane&15, row=(lane>>4)*4+reg.
// ---------------------------------------------------------------------------
__global__ __launch_bounds__(256)
void k_boundary(const float* x,
                const float* bdW1, const float* bdb1,
                const float* bdW2, const float* bdb2,
                const float* bdW3, const float* bdb3,
                float* bws)
{
    __shared__ __align__(16) _Float16 Xh[64][136];
    __shared__ __align__(16) char wbuf[17408];   // W1t[64][136]; later Bh1[64][72] @0 + W2t[32][72] @9216
    __shared__ float b1s[64];
    __shared__ float b2s[32];
    __shared__ float W3s[32];
    __shared__ float b3s[1];

    _Float16 (*W1t)[136] = (_Float16(*)[136])wbuf;
    _Float16 (*Bh1)[72]  = (_Float16(*)[72])wbuf;
    _Float16 (*W2t)[72]  = (_Float16(*)[72])(wbuf + 9216);

    const int t    = threadIdx.x;
    const int et   = blockIdx.y;
    const int R0   = blockIdx.x * 64;
    const int rowsLeft = NN - R0;
    const int w    = t >> 6;
    const int lane = t & 63;
    const int lc   = lane & 15;
    const int lk   = (lane >> 4) << 3;
    const int arow = (w << 4) + lc;
    const int hrow0 = (w << 4) + ((lane >> 4) << 2);

    {   // stage X -> f16 (coalesced float4 reads)
        const float* xb = x + ((long)et * NN + R0) * DD;
        #pragma unroll
        for (int i = 0; i < 8; i++){
            int idx = i * 256 + t;
            int row = idx >> 5;
            int c4  = (idx & 31) << 2;
            float4 v = make_float4(0.f, 0.f, 0.f, 0.f);
            if (row < rowsLeft) v = *(const float4*)(xb + row * DD + c4);
            union { _Float16 h[4]; uint2 u; } pk;
            pk.h[0] = (_Float16)v.x; pk.h[1] = (_Float16)v.y;
            pk.h[2] = (_Float16)v.z; pk.h[3] = (_Float16)v.w;
            *(uint2*)&Xh[row][c4] = pk.u;
        }
    }
    {   // stage W1^T: bdW1 [128][64] -> W1t[n][k] f16 (2048 float4)
        const float* Wg = bdW1 + et * 8192;
        #pragma unroll
        for (int i = 0; i < 8; i++){
            int idx = i * 256 + t;
            int k   = idx >> 4;
            int n4  = (idx & 15) << 2;
            float4 wv = *(const float4*)(Wg + k * 64 + n4);
            W1t[n4 + 0][k] = (_Float16)wv.x;
            W1t[n4 + 1][k] = (_Float16)wv.y;
            W1t[n4 + 2][k] = (_Float16)wv.z;
            W1t[n4 + 3][k] = (_Float16)wv.w;
        }
    }
    if (t < 64)        b1s[t]      = bdb1[et * 64 + t];
    else if (t < 96)   b2s[t - 64] = bdb2[et * 32 + (t - 64)];
    else if (t < 128)  W3s[t - 96] = bdW3[et * 32 + (t - 96)];
    else if (t == 128) b3s[0]      = bdb3[et];
    __syncthreads();

    // GEMM1: h1 = X @ W1   [64x64], K=128
    f32x4 acc[4];
    #pragma unroll
    for (int nt = 0; nt < 4; nt++) acc[nt] = (f32x4){0.f, 0.f, 0.f, 0.f};
    #pragma unroll
    for (int s = 0; s < 4; s++){
        f16x8 af = *(const f16x8*)&Xh[arow][s * 32 + lk];
        #pragma unroll
        for (int nt = 0; nt < 4; nt++){
            f16x8 bf = *(const f16x8*)&W1t[nt * 16 + lc][s * 32 + lk];
            acc[nt] = __builtin_amdgcn_mfma_f32_16x16x32_f16(af, bf, acc[nt], 0, 0, 0);
        }
    }
    __syncthreads();   // W1t reads done; Bh1 aliases its space

    // Bh1 = relu(acc + b1) -> f16  (D layout scalar stores)
    #pragma unroll
    for (int nt = 0; nt < 4; nt++){
        int col = nt * 16 + lc;
        float bias = b1s[col];
        #pragma unroll
        for (int r = 0; r < 4; r++){
            float v = acc[nt][r] + bias;
            Bh1[hrow0 + r][col] = (_Float16)(v > 0.f ? v : 0.f);
        }
    }
    {   // stage W2^T: bdW2 [64][32] -> W2t[n][k] f16 (512 float4)
        const float* Wg = bdW2 + et * 2048;
        #pragma unroll
        for (int i = 0; i < 2; i++){
            int idx = i * 256 + t;
            int k   = idx >> 3;
            int n4  = (idx & 7) << 2;
            float4 wv = *(const float4*)(Wg + k * 32 + n4);
            W2t[n4 + 0][k] = (_Float16)wv.x;
            W2t[n4 + 1][k] = (_Float16)wv.y;
            W2t[n4 + 2][k] = (_Float16)wv.z;
            W2t[n4 + 3][k] = (_Float16)wv.w;
        }
    }
    __syncthreads();

    // GEMM2: h2 = h1 @ W2   [64x32], K=64
    f32x4 acc2[2];
    acc2[0] = (f32x4){0.f, 0.f, 0.f, 0.f};
    acc2[1] = (f32x4){0.f, 0.f, 0.f, 0.f};
    #pragma unroll
    for (int s = 0; s < 2; s++){
        f16x8 af = *(const f16x8*)&Bh1[arow][s * 32 + lk];
        #pragma unroll
        for (int nt = 0; nt < 2; nt++){
            f16x8 bf = *(const f16x8*)&W2t[nt * 16 + lc][s * 32 + lk];
            acc2[nt] = __builtin_amdgcn_mfma_f32_16x16x32_f16(af, bf, acc2[nt], 0, 0, 0);
        }
    }

    // phase 3 in-register: per-row dot32(relu(h2+b2), W3) via lane-group reduce.
    float part[4];
    #pragma unroll
    for (int r = 0; r < 4; r++){
        float p = 0.f;
        #pragma unroll
        for (int nt = 0; nt < 2; nt++){
            int col = nt * 16 + lc;
            float v = acc2[nt][r] + b2s[col];
            v = v > 0.f ? v : 0.f;
            p += v * W3s[col];
        }
        part[r] = p;
    }
    #pragma unroll
    for (int r = 0; r < 4; r++){
        part[r] += __shfl_xor(part[r], 1);
        part[r] += __shfl_xor(part[r], 2);
        part[r] += __shfl_xor(part[r], 4);
        part[r] += __shfl_xor(part[r], 8);
    }
    if (lc == 0){
        #pragma unroll
        for (int r = 0; r < 4; r++){
            int row = R0 + hrow0 + r;
            if (row < NN){
                float b = 1.0f / (1.0f + expf(-(part[r] + b3s[0])));
                bws[et * NN + row] = b;
            }
        }
    }
}

// ---------------------------------------------------------------------------
// K2: edge transform  t = relu(x@W1+b1)@W2+b2  -> bf16 [2,N,128]  via MFMA.
// (round-8 verified: 127.8us fp32 -> <84us; absmax unchanged)
// ---------------------------------------------------------------------------
__global__ __launch_bounds__(256)
void k_edgetrans(const float* x,
                 const float* etW1, const float* etb1,
                 const float* etW2, const float* etb2,
                 u16* tws)
{
    __shared__ __align__(16) _Float16 Ah[64][136];   // X (f16), then H
    __shared__ __align__(16) _Float16 Wt[128][136];  // W1^T, then W2^T
    __shared__ float b1s[128];
    __shared__ float b2s[128];

    const int t    = threadIdx.x;
    const int et   = blockIdx.y;
    const int R0   = blockIdx.x * 64;
    const int rowsLeft = NN - R0;
    const int w    = t >> 6;
    const int lane = t & 63;
    const int lc   = lane & 15;          // col-within-tile / A-row offset
    const int lk   = (lane >> 4) << 3;   // k-group base: 0,8,16,24
    const int arow = (w << 4) + lc;      // this lane's A row (0..63)

    {   // stage X -> f16 (coalesced float4 reads, 8B LDS writes)
        const float* xb = x + ((long)et * NN + R0) * DD;
        #pragma unroll
        for (int i = 0; i < 8; i++){
            int idx = i * 256 + t;
            int row = idx >> 5;
            int c4  = (idx & 31) << 2;
            float4 v = make_float4(0.f, 0.f, 0.f, 0.f);
            if (row < rowsLeft) v = *(const float4*)(xb + row * DD + c4);
            union { _Float16 h[4]; uint2 u; } pk;
            pk.h[0] = (_Float16)v.x; pk.h[1] = (_Float16)v.y;
            pk.h[2] = (_Float16)v.z; pk.h[3] = (_Float16)v.w;
            *(uint2*)&Ah[row][c4] = pk.u;
        }
    }
    {   // stage W1 transposed -> f16
        const float* Wg = etW1 + et * 16384;
        #pragma unroll
        for (int i = 0; i < 16; i++){
            int idx = i * 256 + t;
            int k   = idx >> 5;
            int n4  = (idx & 31) << 2;
            float4 wv = *(const float4*)(Wg + k * 128 + n4);
            Wt[n4 + 0][k] = (_Float16)wv.x;
            Wt[n4 + 1][k] = (_Float16)wv.y;
            Wt[n4 + 2][k] = (_Float16)wv.z;
            Wt[n4 + 3][k] = (_Float16)wv.w;
        }
    }
    if (t < 128) b1s[t] = etb1[et * 128 + t];
    else         b2s[t - 128] = etb2[et * 128 + (t - 128)];
    __syncthreads();

    // GEMM1: h = X @ W1  (acc in fp32)
    f32x4 acc[8];
    #pragma unroll
    for (int nt = 0; nt < 8; nt++) acc[nt] = (f32x4){0.f, 0.f, 0.f, 0.f};
    #pragma unroll
    for (int s = 0; s < 4; s++){
        f16x8 af = *(const f16x8*)&Ah[arow][s * 32 + lk];
        #pragma unroll
        for (int nt = 0; nt < 8; nt++){
            f16x8 bf = *(const f16x8*)&Wt[nt * 16 + lc][s * 32 + lk];
            acc[nt] = __builtin_amdgcn_mfma_f32_16x16x32_f16(af, bf, acc[nt], 0, 0, 0);
        }
    }
    __syncthreads();   // all GEMM1 LDS reads done before overwriting Ah/Wt

    // H = relu(acc + b1) -> f16 into Ah (D layout: col=lane&15, row=(lane>>4)*4+r)
    {
        const int hrow0 = (w << 4) + ((lane >> 4) << 2);
        #pragma unroll
        for (int nt = 0; nt < 8; nt++){
            int col = nt * 16 + lc;
            float bias = b1s[col];
            #pragma unroll
            for (int r = 0; r < 4; r++){
                float v = acc[nt][r] + bias;
                Ah[hrow0 + r][col] = (_Float16)(v > 0.f ? v : 0.f);
            }
        }
    }
    {   // stage W2 transposed -> f16 (over W1)
        const float* Wg = etW2 + et * 16384;
        #pragma unroll
        for (int i = 0; i < 16; i++){
            int idx = i * 256 + t;
            int k   = idx >> 5;
            int n4  = (idx & 31) << 2;
            float4 wv = *(const float4*)(Wg + k * 128 + n4);
            Wt[n4 + 0][k] = (_Float16)wv.x;
            Wt[n4 + 1][k] = (_Float16)wv.y;
            Wt[n4 + 2][k] = (_Float16)wv.z;
            Wt[n4 + 3][k] = (_Float16)wv.w;
        }
    }
    __syncthreads();

    // GEMM2: t = H @ W2
    f32x4 acc2[8];
    #pragma unroll
    for (int nt = 0; nt < 8; nt++) acc2[nt] = (f32x4){0.f, 0.f, 0.f, 0.f};
    #pragma unroll
    for (int s = 0; s < 4; s++){
        f16x8 af = *(const f16x8*)&Ah[arow][s * 32 + lk];
        #pragma unroll
        for (int nt = 0; nt < 8; nt++){
            f16x8 bf = *(const f16x8*)&Wt[nt * 16 + lc][s * 32 + lk];
            acc2[nt] = __builtin_amdgcn_mfma_f32_16x16x32_f16(af, bf, acc2[nt], 0, 0, 0);
        }
    }

    // store t + b2 as bf16 (D layout scalar stores; block region is contiguous
    // so L2 assembles full lines)
    {
        const int hrow0 = (w << 4) + ((lane >> 4) << 2);
        #pragma unroll
        for (int nt = 0; nt < 8; nt++){
            int col = nt * 16 + lc;
            float bias = b2s[col];
            #pragma unroll
            for (int r = 0; r < 4; r++){
                int grow = R0 + hrow0 + r;
                if (grow < NN)
                    tws[((long)et * NN + grow) * DD + col] = f2bf(acc2[nt][r] + bias);
            }
        }
    }
}

// ---------------------------------------------------------------------------
// K3: histogram of edges by dst:  deg[et][dst]++
// ---------------------------------------------------------------------------
__global__ __launch_bounds__(256)
void k_hist(const int* ei, int* deg)
{
    const int et = blockIdx.y;
    int e = blockIdx.x * 256 + threadIdx.x;
    int dst = ei[(et * 2 + 1) * EE + e];
    atomicAdd(&deg[et * NN + dst], 1);
}

// ---------------------------------------------------------------------------
// K3a: per-edge coefficient MLP, COALESCED output (no scatter).
// One edge per thread, STRAIGHT-LINE MLP -- never put this MLP in a loop:
// LICM hoists the loop-invariant LDS weight reads into registers, hits the
// 256-VGPR cap, and spills h1/h2 to scratch (round 4/6: 630 MB scratch
// FETCH, 517 us; #pragma unroll 1 does NOT prevent it). This straight-line
// form measured 60-72 VGPR in rounds 0-3.
// Output record: src | f2h(ea*coef)<<16, written to crec[et*EE+e].
// ---------------------------------------------------------------------------
__global__ __launch_bounds__(256)
void k_coef(const int* ei, const float* ea,
            const float* bwW1, const float* bwb1,
            const float* bwW2, const float* bwb2,
            const float* bwW3, const float* bwb3,
            const float* bws,
            unsigned int* crec)
{
    __shared__ float W1s[64];
    __shared__ float b1sh[32];
    __shared__ float W2s[512];
    __shared__ float b2sh[16];
    __shared__ float W3s[16];
    __shared__ float b3sh[1];
    const int t  = threadIdx.x;
    const int et = blockIdx.y;

    if (t < 64)        W1s[t]        = bwW1[et * 64 + t];
    else if (t < 96)   b1sh[t - 64]  = bwb1[et * 32 + (t - 64)];
    else if (t < 112)  b2sh[t - 96]  = bwb2[et * 16 + (t - 96)];
    else if (t < 128)  W3s[t - 112]  = bwW3[et * 16 + (t - 112)];
    else if (t == 128) b3sh[0]       = bwb3[et];
    for (int idx = t; idx < 512; idx += 256)
        W2s[idx] = bwW2[et * 512 + idx];
    __syncthreads();

    int e   = blockIdx.x * 256 + t;
    int src = ei[(et * 2 + 0) * EE + e];
    int dst = ei[(et * 2 + 1) * EE + e];
    float sb = bws[et * NN + src];
    float db = bws[(1 - et) * NN + dst];

    float h1[32];
    #pragma unroll
    for (int j = 0; j < 32; j++){
        float v = sb * W1s[j] + db * W1s[32 + j] + b1sh[j];
        h1[j] = v > 0.0f ? v : 0.0f;
    }
    float h2[16];
    #pragma unroll
    for (int k = 0; k < 16; k++) h2[k] = b2sh[k];
    #pragma unroll
    for (int j = 0; j < 32; j++){
        float hv = h1[j];
        #pragma unroll
        for (int k = 0; k < 16; k++)
            h2[k] += hv * W2s[j * 16 + k];
    }
    float z = b3sh[0];
    #pragma unroll
    for (int k = 0; k < 16; k++){
        float hv = h2[k] > 0.0f ? h2[k] : 0.0f;
        z += hv * W3s[k];
    }
    float wv = 1.0f / (1.0f + expf(-z));
    if (sb > THRV || db > THRV) wv *= 2.0f;
    float c = ea[et * EE + e] * wv;

    crec[(long)et * EE + e] = (unsigned int)src | ((unsigned int)f2h(c) << 16);
}

// ---------------------------------------------------------------------------
// K3b: bucket scatter (pass A of the two-pass placement sort).
// Each 2048-edge block counts per-bucket in LDS, reserves a contiguous
// chunk per bucket with ONE global atomic, writes records into its chunk
// -> lines filled by a single block/XCD -> full-line evictions.
// Record: .x = finished 4B record from k_coef, .y = dst_local (0..255).
// ---------------------------------------------------------------------------
__global__ __launch_bounds__(256)
void k_bucket2(const int* ei, const unsigned int* crec, int* bcur, uint2* barr)
{
    __shared__ int hist[NB];
    __shared__ int gbase[NB];
    const int t    = threadIdx.x;
    const int et   = blockIdx.y;
    const int base = blockIdx.x * 2048;

    for (int i = t; i < NB; i += 256) hist[i] = 0;
    __syncthreads();

    int dlv[8], bv[8], lv[8];
    unsigned int rv[8];
    #pragma unroll
    for (int j = 0; j < 8; j++){
        int e = base + j * 256 + t;
        bv[j] = -1;
        if (e < EE){
            int dst = ei[(et * 2 + 1) * EE + e];
            dlv[j]  = dst & 255;
            bv[j]   = dst >> 8;
            rv[j]   = crec[(long)et * EE + e];
            lv[j]   = atomicAdd(&hist[bv[j]], 1);
        }
    }
    __syncthreads();
    if (t < NB) gbase[t] = atomicAdd(&bcur[et * NB + t], hist[t]);
    __syncthreads();
    #pragma unroll
    for (int j = 0; j < 8; j++){
        if (bv[j] >= 0){
            int pos = gbase[bv[j]] + lv[j];
            uint2 r;
            r.x = rv[j];
            r.y = (unsigned int)dlv[j];
            barr[(long)(et * NB + bv[j]) * BCAP + pos] = r;
        }
    }
}

// ---------------------------------------------------------------------------
// K4a: local scan — each block scans 2048 elems (8/thread serial + 256-wide
// Hillis-Steele); writes local-exclusive values to rowptr, block total to bsum
// ---------------------------------------------------------------------------
__global__ __launch_bounds__(256)
void k_scan_local(const int* deg, int* rowptr, int* bsum)
{
    __shared__ int tsum[256];
    const int et  = blockIdx.y;
    const int blk = blockIdx.x;
    const int t   = threadIdx.x;
    const int base = blk * 2048 + t * 8;

    int v[8];
    int run = 0;
    #pragma unroll
    for (int j = 0; j < 8; j++){
        int i = base + j;
        int d = (i < NN) ? deg[et * NN + i] : 0;
        v[j] = run;            // thread-local exclusive prefix
        run += d;
    }
    tsum[t] = run;
    __syncthreads();
    #pragma unroll
    for (int off = 1; off < 256; off <<= 1){
        int a = (t >= off) ? tsum[t - off] : 0;
        __syncthreads();
        tsum[t] += a;
        __syncthreads();
    }
    int excl = tsum[t] - run;   // exclusive prefix of this thread within block
    #pragma unroll
    for (int j = 0; j < 8; j++){
        int i = base + j;
        if (i < NN) rowptr[et * NN + i] = excl + v[j];
    }
    if (t == 255) bsum[et * SCAN_BLK + blk] = tsum[255];
}

// ---------------------------------------------------------------------------
// K4b: scan the 25 block sums per et (trivial, 1 block, 2 active threads)
// ---------------------------------------------------------------------------
__global__ __launch_bounds__(64)
void k_scan_bsum(int* bsum, int* boff)
{
    int et = threadIdx.x;
    if (et < 2){
        int run = 0;
        for (int b = 0; b < SCAN_BLK; b++){
            int d = bsum[et * SCAN_BLK + b];
            boff[et * SCAN_BLK + b] = run;
            run += d;
        }
    }
}

// ---------------------------------------------------------------------------
// K4c: add block offsets; emit final rowptr (coalesced)
// ---------------------------------------------------------------------------
__global__ __launch_bounds__(256)
void k_scan_add(int* rowptr, const int* boff)
{
    const int et  = blockIdx.y;
    const int blk = blockIdx.x;
    const int t   = threadIdx.x;
    const int off = boff[et * SCAN_BLK + blk];
    #pragma unroll
    for (int j = 0; j < 8; j++){
        int i = blk * 2048 + j * 256 + t;
        if (i < NN)
            rowptr[et * NN + i] += off;
    }
}

// ---------------------------------------------------------------------------
// K5: pass B of the sort — pure placement, NO MLP (body is ~6 instructions,
// nothing for LICM to hoist). One block per (et,bucket); LDS cursors from
// rowptr; the bucket's epair region is contiguous and block-exclusive ->
// full-line writes.
// ---------------------------------------------------------------------------
__global__ __launch_bounds__(256)
void k_sortb(const uint2* barr, const int* bcur, const int* rowptr,
             unsigned int* epair)
{
    __shared__ int curs[256];
    const int t    = threadIdx.x;
    const int b    = blockIdx.x;
    const int et   = blockIdx.y;
    const int dst0 = b * 256;

    {
        int d = dst0 + t;
        if (d < NN) curs[t] = rowptr[et * NN + d];
    }
    __syncthreads();

    const int cnt = bcur[et * NB + b];
    const uint2* bb = barr + (long)(et * NB + b) * BCAP;

    for (int r = t; r < cnt; r += 256){
        uint2 rec = bb[r];
        int pos = atomicAdd(&curs[rec.y], 1);
        epair[(long)et * EE + pos] = rec.x;
    }
}

// ---------------------------------------------------------------------------
// K6: CSR gather — one wave per dst node, 2 dims per lane, fp32 registers.
// Predicated unroll-8: 8 independent tws-row loads in flight per wave.
// Records are 4B (src u16 | coef fp16); tail slots clamp to record 0 with
// the coef bits masked to 0, branch-free inner loop.
// ---------------------------------------------------------------------------
__global__ __launch_bounds__(256)
void k_gather(const int* rowptr, const int* deg,
              const unsigned int* epair, const u16* tws, float* agg)
{
    const int et   = blockIdx.y;
    const int w    = threadIdx.x >> 6;
    const int lane = threadIdx.x & 63;
    const int n    = blockIdx.x * 4 + w;          // 12500*4 = 50000 exactly

    int start = rowptr[et * NN + n];
    int cnt   = deg[et * NN + n];
    const unsigned int* ep = epair + (long)et * EE + start;
    const u16* tbase = tws + (long)et * NN * DD + lane * 2;

    float a0 = 0.0f, a1 = 0.0f;
    for (int k = 0; k < cnt; k += 8){
        unsigned int q[8];
        #pragma unroll
        for (int u = 0; u < 8; u++){
            int idx = k + u;
            q[u] = ep[idx < cnt ? idx : 0];
            if (idx >= cnt) q[u] &= 0xffffu;      // coef bits := 0 for tail
        }
        unsigned int pv[8];
        #pragma unroll
        for (int u = 0; u < 8; u++)
            pv[u] = *(const unsigned int*)(tbase + (long)(q[u] & 0xffffu) * DD);
        #pragma unroll
        for (int u = 0; u < 8; u++){
            float c = h2f((u16)(q[u] >> 16));
            a0 += bf2f((u16)(pv[u] & 0xffffu)) * c;
            a1 += bf2f((u16)(pv[u] >> 16)) * c;
        }
    }
    float* op = agg + ((long)(1 - et) * NN + n) * DD + lane * 2;
    op[0] = a0;
    op[1] = a1;
}

// ---------------------------------------------------------------------------
// K7: U = agg + x; z = U@nuW + nub; LayerNorm; relu -> out fp32
// (fp32 vector version — round-9 verified at 83.5us. NOTE: the round-10
// MFMA port of this kernel FAILED absmax 0.137 vs 0.094 for reasons that
// precision arithmetic cannot explain (f16 error bound ~0.002) and layout
// bugs cannot explain (identical mappings pass in k_boundary/k_edgetrans).
// Do not retry the MFMA port without a device-side diagnostic.)
// ---------------------------------------------------------------------------
__global__ __launch_bounds__(256)
void k_final(const float* agg, const float* x,
             const float* nuW, const float* nub,
             const float* lng, const float* lnb,
             float* out)
{
    __shared__ __align__(16) float Us[64 * 132];
    __shared__ float nubs[128], lngs[128], lnbs[128];

    const int t  = threadIdx.x;
    const int et = blockIdx.y;
    const int R0 = blockIdx.x * 64;
    const int rowsLeft = NN - R0;

    {   // coalesced float4 staging of U = agg + x
        const float* xb = x   + ((long)et * NN + R0) * DD;
        const float* ab = agg + ((long)et * NN + R0) * DD;
        #pragma unroll
        for (int i = 0; i < 8; i++){
            int idx = i * 256 + t;
            int row = idx >> 5;
            int c4  = (idx & 31) << 2;
            float4 v = make_float4(0.f, 0.f, 0.f, 0.f);
            if (row < rowsLeft){
                float4 xv4 = *(const float4*)(xb + row * DD + c4);
                float4 av4 = *(const float4*)(ab + row * DD + c4);
                v.x = xv4.x + av4.x; v.y = xv4.y + av4.y;
                v.z = xv4.z + av4.z; v.w = xv4.w + av4.w;
            }
            *(float4*)&Us[row * 132 + c4] = v;
        }
    }
    if (t < 128) nubs[t] = nub[et * 128 + t];
    else {
        lngs[t - 128] = lng[et * 128 + (t - 128)];
        lnbs[t - 128] = lnb[et * 128 + (t - 128)];
    }
    __syncthreads();

    const int tc = t & 15, tr = t >> 4;
    const float* Wg = nuW + et * 16384;    // [128][128], L2-resident
    float acc[4][8];
    for (int m = 0; m < 4; m++)
        for (int j = 0; j < 8; j++) acc[m][j] = 0.0f;
    for (int k = 0; k < 128; k++){
        float4 wv0 = *(const float4*)(Wg + k * 128 + tc * 8);
        float4 wv1 = *(const float4*)(Wg + k * 128 + tc * 8 + 4);
        float xv[4];
        #pragma unroll
        for (int m = 0; m < 4; m++) xv[m] = Us[(tr + 16 * m) * 132 + k];
        #pragma unroll
        for (int m = 0; m < 4; m++){
            acc[m][0] += xv[m] * wv0.x; acc[m][1] += xv[m] * wv0.y;
            acc[m][2] += xv[m] * wv0.z; acc[m][3] += xv[m] * wv0.w;
            acc[m][4] += xv[m] * wv1.x; acc[m][5] += xv[m] * wv1.y;
            acc[m][6] += xv[m] * wv1.z; acc[m][7] += xv[m] * wv1.w;
        }
    }

    // z = acc + nub; in-register LayerNorm per row (16 tc-lanes hold a row)
    for (int m = 0; m < 4; m++){
        float z[8];
        float s = 0.0f, ss = 0.0f;
        #pragma unroll
        for (int j = 0; j < 8; j++){
            z[j] = acc[m][j] + nubs[tc * 8 + j];
            s += z[j]; ss += z[j] * z[j];
        }
        s  += __shfl_xor(s, 1);  s  += __shfl_xor(s, 2);
        s  += __shfl_xor(s, 4);  s  += __shfl_xor(s, 8);
        ss += __shfl_xor(ss, 1); ss += __shfl_xor(ss, 2);
        ss += __shfl_xor(ss, 4); ss += __shfl_xor(ss, 8);
        float mean = s * (1.0f / 128.0f);
        float var  = ss * (1.0f / 128.0f) - mean * mean;
        float rstd = rsqrtf(var + 1e-5f);
        int grow = R0 + tr + 16 * m;
        if (grow < NN){
            float4 o0, o1;
            float o[8];
            #pragma unroll
            for (int j = 0; j < 8; j++){
                int col = tc * 8 + j;
                float v = (z[j] - mean) * rstd * lngs[col] + lnbs[col];
                o[j] = v > 0.0f ? v : 0.0f;
            }
            o0.x = o[0]; o0.y = o[1]; o0.z = o[2]; o0.w = o[3];
            o1.x = o[4]; o1.y = o[5]; o1.z = o[6]; o1.w = o[7];
            float* op = out + ((long)et * NN + grow) * DD + tc * 8;
            *(float4*)(op)     = o0;
            *(float4*)(op + 4) = o1;
        }
    }
}

// ---------------------------------------------------------------------------
extern "C" void kernel_launch(void* const* d_in, const int* in_sizes, int n_in,
                              void* d_out, int out_size, void* d_ws, size_t ws_size,
                              hipStream_t stream)
{
    const float* x    = (const float*)d_in[0];
    const int*   ei   = (const int*)d_in[1];
    const float* ea   = (const float*)d_in[2];
    const float* bdW1 = (const float*)d_in[3];
    const float* bdb1 = (const float*)d_in[4];
    const float* bdW2 = (const float*)d_in[5];
    const float* bdb2 = (const float*)d_in[6];
    const float* bdW3 = (const float*)d_in[7];
    const float* bdb3 = (const float*)d_in[8];
    const float* etW1 = (const float*)d_in[9];
    const float* etb1 = (const float*)d_in[10];
    const float* etW2 = (const float*)d_in[11];
    const float* etb2 = (const float*)d_in[12];
    const float* bwW1 = (const float*)d_in[13];
    const float* bwb1 = (const float*)d_in[14];
    const float* bwW2 = (const float*)d_in[15];
    const float* bwb2 = (const float*)d_in[16];
    const float* bwW3 = (const float*)d_in[17];
    const float* bwb3 = (const float*)d_in[18];
    const float* nuW  = (const float*)d_in[19];
    const float* nub  = (const float*)d_in[20];
    const float* lng  = (const float*)d_in[21];
    const float* lnb  = (const float*)d_in[22];

    // workspace layout (bytes):
    //   agg    [2*N*128] f32 : 51,200,000   @ 0
    //     aliased (both dead before k_gather overwrites all of agg):
    //       barr [2*NB*BCAP] uint2 = 16,056,320  @ 0
    //       crec [2*E]       u32   =  6,400,000  @ 17,000,000
    //   tws    [2*N*128] bf16: 25,600,000   @ 51,200,000
    //   bws    [2*N]     f32 :    400,000   @ 76,800,000
    //   deg    [2*N]     i32 :    400,000   @ 77,200,000
    //   bcur   [2*NB]    i32 :      1,568   @ 77,600,000   (zeroed with deg)
    //   rowptr [2*N]     i32 :    400,000   @ 77,602,048
    //   epair  [2*E]     u32 :  6,400,000   @ 78,002,048
    //   bsum   [2*25]    i32 :        200   @ 84,402,048
    //   boff   [2*25]    i32 :        200   @ 84,402,560
    char*  wsb    = (char*)d_ws;
    float* agg    = (float*)(wsb);
    uint2* barr   = (uint2*)(wsb);
    unsigned int* crec = (unsigned int*)(wsb + 17000000L);
    u16*   tws    = (u16*)  (wsb + 51200000L);
    float* bws    = (float*)(wsb + 76800000L);
    int*   deg    = (int*)  (wsb + 77200000L);
    int*   bcur   = (int*)  (wsb + 77600000L);
    int*   rowptr = (int*)  (wsb + 77602048L);
    unsigned int* epair = (unsigned int*)(wsb + 78002048L);
    int*   bsum   = (int*)  (wsb + 84402048L);
    int*   boff   = (int*)  (wsb + 84402560L);

    dim3 blk(256);
    // zero deg (2*NN) and bcur (2*NB) in one contiguous pass
    k_zero<<<dim3((2 * NN + 2 * NB + 255) / 256 + 1), blk, 0, stream>>>(deg, 2 * NN + 512);

    dim3 g1((NN + 63) / 64, 2);
    k_boundary <<<g1, blk, 0, stream>>>(x, bdW1, bdb1, bdW2, bdb2, bdW3, bdb3, bws);
    k_edgetrans<<<g1, blk, 0, stream>>>(x, etW1, etb1, etW2, etb2, tws);

    dim3 ge(EE / 256, 2);    // 800000/256 = 3125 exactly
    k_hist<<<ge, blk, 0, stream>>>(ei, deg);

    k_coef<<<ge, blk, 0, stream>>>(ei, ea, bwW1, bwb1, bwW2, bwb2, bwW3, bwb3,
                                   bws, crec);

    dim3 gb((EE + 2047) / 2048, 2);   // 391 blocks, 2048 edges each
    k_bucket2<<<gb, blk, 0, stream>>>(ei, crec, bcur, barr);

    dim3 gs(SCAN_BLK, 2);
    k_scan_local<<<gs, blk, 0, stream>>>(deg, rowptr, bsum);
    k_scan_bsum <<<dim3(1), dim3(64), 0, stream>>>(bsum, boff);
    k_scan_add  <<<gs, blk, 0, stream>>>(rowptr, boff);

    dim3 gp(NB, 2);   // one block per (et, bucket)
    k_sortb<<<gp, blk, 0, stream>>>(barr, bcur, rowptr, epair);

    k_gather<<<dim3(NN / 4, 2), blk, 0, stream>>>(rowptr, deg, epair, tws, agg);

    k_final<<<g1, blk, 0, stream>>>(agg, x, nuW, nub, lng, lnb, (float*)d_out);
}

// Round 12
// 523.510 us; speedup vs baseline: 1.0206x; 1.0206x over previous
//
#include <hip/hip_runtime.h>

#define NN 50000
#define DD 128
#define EE 800000
#define THRV 0.3f
#define SCAN_BLK 25           // ceil(50000 / 2048)
#define NB 196                // ceil(50000 / 256) dst-buckets of 256 nodes
#define BCAP 5120             // bucket capacity; mean 4096, sigma ~64 -> 16 sigma

typedef unsigned short u16;
typedef _Float16 f16x8 __attribute__((ext_vector_type(8)));
typedef float    f32x4 __attribute__((ext_vector_type(4)));

__device__ __forceinline__ float bf2f(u16 u){
    union { unsigned int i; float f; } v; v.i = ((unsigned int)u) << 16; return v.f;
}
__device__ __forceinline__ u16 f2bf(float f){
    unsigned int x = __float_as_uint(f);
    unsigned int r = (x + 0x7fffu + ((x >> 16) & 1u)) >> 16;
    return (u16)r;
}
__device__ __forceinline__ u16 f2h(float f){
    union { _Float16 h; u16 u; } v; v.h = (_Float16)f; return v.u;
}
__device__ __forceinline__ float h2f(u16 u){
    union { _Float16 h; u16 u; } v; v.u = u; return (float)v.h;
}

// ---------------------------------------------------------------------------
// K0: zero degree counters + bucket cursors (contiguous in workspace)
// ---------------------------------------------------------------------------
__global__ __launch_bounds__(256)
void k_zero(int* p, int n)
{
    int i = blockIdx.x * 256 + threadIdx.x;
    if (i < n) p[i] = 0;
}

// ---------------------------------------------------------------------------
// K1: boundary MLP via MFMA.  b = sigmoid(relu(relu(x@W1+b1)@W2+b2)@W3+b3)
// (round-9 verified: 85us fp32 -> out of top-5; absmax unchanged)
// m89 layouts: A: lane l = A[l&15][(l>>4)*8..+7]; B: lane l = B[(l>>4)*8..+7][l&15]
// (W staged TRANSPOSED); C/D: col=lane&15, row=(lane>>4)*4+reg.
// ---------------------------------------------------------------------------
__global__ __launch_bounds__(256)
void k_boundary(const float* x,
                const float* bdW1, const float* bdb1,
                const float* bdW2, const float* bdb2,
                const float* bdW3, const float* bdb3,
                float* bws)
{
    __shared__ __align__(16) _Float16 Xh[64][136];
    __shared__ __align__(16) char wbuf[17408];   // W1t[64][136]; later Bh1[64][72] @0 + W2t[32][72] @9216
    __shared__ float b1s[64];
    __shared__ float b2s[32];
    __shared__ float W3s[32];
    __shared__ float b3s[1];

    _Float16 (*W1t)[136] = (_Float16(*)[136])wbuf;
    _Float16 (*Bh1)[72]  = (_Float16(*)[72])wbuf;
    _Float16 (*W2t)[72]  = (_Float16(*)[72])(wbuf + 9216);

    const int t    = threadIdx.x;
    const int et   = blockIdx.y;
    const int R0   = blockIdx.x * 64;
    const int rowsLeft = NN - R0;
    const int w    = t >> 6;
    const int lane = t & 63;
    const int lc   = lane & 15;
    const int lk   = (lane >> 4) << 3;
    const int arow = (w << 4) + lc;
    const int hrow0 = (w << 4) + ((lane >> 4) << 2);

    {   // stage X -> f16 (coalesced float4 reads)
        const float* xb = x + ((long)et * NN + R0) * DD;
        #pragma unroll
        for (int i = 0; i < 8; i++){
            int idx = i * 256 + t;
            int row = idx >> 5;
            int c4  = (idx & 31) << 2;
            float4 v = make_float4(0.f, 0.f, 0.f, 0.f);
            if (row < rowsLeft) v = *(const float4*)(xb + row * DD + c4);
            union { _Float16 h[4]; uint2 u; } pk;
            pk.h[0] = (_Float16)v.x; pk.h[1] = (_Float16)v.y;
            pk.h[2] = (_Float16)v.z; pk.h[3] = (_Float16)v.w;
            *(uint2*)&Xh[row][c4] = pk.u;
        }
    }
    {   // stage W1^T: bdW1 [128][64] -> W1t[n][k] f16 (2048 float4)
        const float* Wg = bdW1 + et * 8192;
        #pragma unroll
        for (int i = 0; i < 8; i++){
            int idx = i * 256 + t;
            int k   = idx >> 4;
            int n4  = (idx & 15) << 2;
            float4 wv = *(const float4*)(Wg + k * 64 + n4);
            W1t[n4 + 0][k] = (_Float16)wv.x;
            W1t[n4 + 1][k] = (_Float16)wv.y;
            W1t[n4 + 2][k] = (_Float16)wv.z;
            W1t[n4 + 3][k] = (_Float16)wv.w;
        }
    }
    if (t < 64)        b1s[t]      = bdb1[et * 64 + t];
    else if (t < 96)   b2s[t - 64] = bdb2[et * 32 + (t - 64)];
    else if (t < 128)  W3s[t - 96] = bdW3[et * 32 + (t - 96)];
    else if (t == 128) b3s[0]      = bdb3[et];
    __syncthreads();

    // GEMM1: h1 = X @ W1   [64x64], K=128
    f32x4 acc[4];
    #pragma unroll
    for (int nt = 0; nt < 4; nt++) acc[nt] = (f32x4){0.f, 0.f, 0.f, 0.f};
    #pragma unroll
    for (int s = 0; s < 4; s++){
        f16x8 af = *(const f16x8*)&Xh[arow][s * 32 + lk];
        #pragma unroll
        for (int nt = 0; nt < 4; nt++){
            f16x8 bf = *(const f16x8*)&W1t[nt * 16 + lc][s * 32 + lk];
            acc[nt] = __builtin_amdgcn_mfma_f32_16x16x32_f16(af, bf, acc[nt], 0, 0, 0);
        }
    }
    __syncthreads();   // W1t reads done; Bh1 aliases its space

    // Bh1 = relu(acc + b1) -> f16  (D layout scalar stores)
    #pragma unroll
    for (int nt = 0; nt < 4; nt++){
        int col = nt * 16 + lc;
        float bias = b1s[col];
        #pragma unroll
        for (int r = 0; r < 4; r++){
            float v = acc[nt][r] + bias;
            Bh1[hrow0 + r][col] = (_Float16)(v > 0.f ? v : 0.f);
        }
    }
    {   // stage W2^T: bdW2 [64][32] -> W2t[n][k] f16 (512 float4)
        const float* Wg = bdW2 + et * 2048;
        #pragma unroll
        for (int i = 0; i < 2; i++){
            int idx = i * 256 + t;
            int k   = idx >> 3;
            int n4  = (idx & 7) << 2;
            float4 wv = *(const float4*)(Wg + k * 32 + n4);
            W2t[n4 + 0][k] = (_Float16)wv.x;
            W2t[n4 + 1][k] = (_Float16)wv.y;
            W2t[n4 + 2][k] = (_Float16)wv.z;
            W2t[n4 + 3][k] = (_Float16)wv.w;
        }
    }
    __syncthreads();

    // GEMM2: h2 = h1 @ W2   [64x32], K=64
    f32x4 acc2[2];
    acc2[0] = (f32x4){0.f, 0.f, 0.f, 0.f};
    acc2[1] = (f32x4){0.f, 0.f, 0.f, 0.f};
    #pragma unroll
    for (int s = 0; s < 2; s++){
        f16x8 af = *(const f16x8*)&Bh1[arow][s * 32 + lk];
        #pragma unroll
        for (int nt = 0; nt < 2; nt++){
            f16x8 bf = *(const f16x8*)&W2t[nt * 16 + lc][s * 32 + lk];
            acc2[nt] = __builtin_amdgcn_mfma_f32_16x16x32_f16(af, bf, acc2[nt], 0, 0, 0);
        }
    }

    // phase 3 in-register: per-row dot32(relu(h2+b2), W3) via lane-group reduce.
    float part[4];
    #pragma unroll
    for (int r = 0; r < 4; r++){
        float p = 0.f;
        #pragma unroll
        for (int nt = 0; nt < 2; nt++){
            int col = nt * 16 + lc;
            float v = acc2[nt][r] + b2s[col];
            v = v > 0.f ? v : 0.f;
            p += v * W3s[col];
        }
        part[r] = p;
    }
    #pragma unroll
    for (int r = 0; r < 4; r++){
        part[r] += __shfl_xor(part[r], 1);
        part[r] += __shfl_xor(part[r], 2);
        part[r] += __shfl_xor(part[r], 4);
        part[r] += __shfl_xor(part[r], 8);
    }
    if (lc == 0){
        #pragma unroll
        for (int r = 0; r < 4; r++){
            int row = R0 + hrow0 + r;
            if (row < NN){
                float b = 1.0f / (1.0f + expf(-(part[r] + b3s[0])));
                bws[et * NN + row] = b;
            }
        }
    }
}

// ---------------------------------------------------------------------------
// K2: edge transform  t = relu(x@W1+b1)@W2+b2  -> bf16 [2,N,128]  via MFMA.
// (round-8 verified: 127.8us fp32 -> <84us; absmax unchanged)
// ---------------------------------------------------------------------------
__global__ __launch_bounds__(256)
void k_edgetrans(const float* x,
                 const float* etW1, const float* etb1,
                 const float* etW2, const float* etb2,
                 u16* tws)
{
    __shared__ __align__(16) _Float16 Ah[64][136];   // X (f16), then H
    __shared__ __align__(16) _Float16 Wt[128][136];  // W1^T, then W2^T
    __shared__ float b1s[128];
    __shared__ float b2s[128];

    const int t    = threadIdx.x;
    const int et   = blockIdx.y;
    const int R0   = blockIdx.x * 64;
    const int rowsLeft = NN - R0;
    const int w    = t >> 6;
    const int lane = t & 63;
    const int lc   = lane & 15;          // col-within-tile / A-row offset
    const int lk   = (lane >> 4) << 3;   // k-group base: 0,8,16,24
    const int arow = (w << 4) + lc;      // this lane's A row (0..63)

    {   // stage X -> f16 (coalesced float4 reads, 8B LDS writes)
        const float* xb = x + ((long)et * NN + R0) * DD;
        #pragma unroll
        for (int i = 0; i < 8; i++){
            int idx = i * 256 + t;
            int row = idx >> 5;
            int c4  = (idx & 31) << 2;
            float4 v = make_float4(0.f, 0.f, 0.f, 0.f);
            if (row < rowsLeft) v = *(const float4*)(xb + row * DD + c4);
            union { _Float16 h[4]; uint2 u; } pk;
            pk.h[0] = (_Float16)v.x; pk.h[1] = (_Float16)v.y;
            pk.h[2] = (_Float16)v.z; pk.h[3] = (_Float16)v.w;
            *(uint2*)&Ah[row][c4] = pk.u;
        }
    }
    {   // stage W1 transposed -> f16
        const float* Wg = etW1 + et * 16384;
        #pragma unroll
        for (int i = 0; i < 16; i++){
            int idx = i * 256 + t;
            int k   = idx >> 5;
            int n4  = (idx & 31) << 2;
            float4 wv = *(const float4*)(Wg + k * 128 + n4);
            Wt[n4 + 0][k] = (_Float16)wv.x;
            Wt[n4 + 1][k] = (_Float16)wv.y;
            Wt[n4 + 2][k] = (_Float16)wv.z;
            Wt[n4 + 3][k] = (_Float16)wv.w;
        }
    }
    if (t < 128) b1s[t] = etb1[et * 128 + t];
    else         b2s[t - 128] = etb2[et * 128 + (t - 128)];
    __syncthreads();

    // GEMM1: h = X @ W1  (acc in fp32)
    f32x4 acc[8];
    #pragma unroll
    for (int nt = 0; nt < 8; nt++) acc[nt] = (f32x4){0.f, 0.f, 0.f, 0.f};
    #pragma unroll
    for (int s = 0; s < 4; s++){
        f16x8 af = *(const f16x8*)&Ah[arow][s * 32 + lk];
        #pragma unroll
        for (int nt = 0; nt < 8; nt++){
            f16x8 bf = *(const f16x8*)&Wt[nt * 16 + lc][s * 32 + lk];
            acc[nt] = __builtin_amdgcn_mfma_f32_16x16x32_f16(af, bf, acc[nt], 0, 0, 0);
        }
    }
    __syncthreads();   // all GEMM1 LDS reads done before overwriting Ah/Wt

    // H = relu(acc + b1) -> f16 into Ah (D layout: col=lane&15, row=(lane>>4)*4+r)
    {
        const int hrow0 = (w << 4) + ((lane >> 4) << 2);
        #pragma unroll
        for (int nt = 0; nt < 8; nt++){
            int col = nt * 16 + lc;
            float bias = b1s[col];
            #pragma unroll
            for (int r = 0; r < 4; r++){
                float v = acc[nt][r] + bias;
                Ah[hrow0 + r][col] = (_Float16)(v > 0.f ? v : 0.f);
            }
        }
    }
    {   // stage W2 transposed -> f16 (over W1)
        const float* Wg = etW2 + et * 16384;
        #pragma unroll
        for (int i = 0; i < 16; i++){
            int idx = i * 256 + t;
            int k   = idx >> 5;
            int n4  = (idx & 31) << 2;
            float4 wv = *(const float4*)(Wg + k * 128 + n4);
            Wt[n4 + 0][k] = (_Float16)wv.x;
            Wt[n4 + 1][k] = (_Float16)wv.y;
            Wt[n4 + 2][k] = (_Float16)wv.z;
            Wt[n4 + 3][k] = (_Float16)wv.w;
        }
    }
    __syncthreads();

    // GEMM2: t = H @ W2
    f32x4 acc2[8];
    #pragma unroll
    for (int nt = 0; nt < 8; nt++) acc2[nt] = (f32x4){0.f, 0.f, 0.f, 0.f};
    #pragma unroll
    for (int s = 0; s < 4; s++){
        f16x8 af = *(const f16x8*)&Ah[arow][s * 32 + lk];
        #pragma unroll
        for (int nt = 0; nt < 8; nt++){
            f16x8 bf = *(const f16x8*)&Wt[nt * 16 + lc][s * 32 + lk];
            acc2[nt] = __builtin_amdgcn_mfma_f32_16x16x32_f16(af, bf, acc2[nt], 0, 0, 0);
        }
    }

    // store t + b2 as bf16 (D layout scalar stores; block region is contiguous
    // so L2 assembles full lines)
    {
        const int hrow0 = (w << 4) + ((lane >> 4) << 2);
        #pragma unroll
        for (int nt = 0; nt < 8; nt++){
            int col = nt * 16 + lc;
            float bias = b2s[col];
            #pragma unroll
            for (int r = 0; r < 4; r++){
                int grow = R0 + hrow0 + r;
                if (grow < NN)
                    tws[((long)et * NN + grow) * DD + col] = f2bf(acc2[nt][r] + bias);
            }
        }
    }
}

// ---------------------------------------------------------------------------
// K3a: per-edge coefficient MLP, COALESCED output (no scatter).
// One edge per thread, STRAIGHT-LINE MLP -- never put this MLP in a loop:
// LICM hoists the loop-invariant LDS weight reads into registers, hits the
// 256-VGPR cap, and spills h1/h2 to scratch (round 4/6: 630 MB scratch
// FETCH, 517 us; #pragma unroll 1 does NOT prevent it). This straight-line
// form measured 60-72 VGPR in rounds 0-3.
// Output record: src | f2h(ea*coef)<<16, written to crec[et*EE+e].
// ---------------------------------------------------------------------------
__global__ __launch_bounds__(256)
void k_coef(const int* ei, const float* ea,
            const float* bwW1, const float* bwb1,
            const float* bwW2, const float* bwb2,
            const float* bwW3, const float* bwb3,
            const float* bws,
            unsigned int* crec)
{
    __shared__ float W1s[64];
    __shared__ float b1sh[32];
    __shared__ float W2s[512];
    __shared__ float b2sh[16];
    __shared__ float W3s[16];
    __shared__ float b3sh[1];
    const int t  = threadIdx.x;
    const int et = blockIdx.y;

    if (t < 64)        W1s[t]        = bwW1[et * 64 + t];
    else if (t < 96)   b1sh[t - 64]  = bwb1[et * 32 + (t - 64)];
    else if (t < 112)  b2sh[t - 96]  = bwb2[et * 16 + (t - 96)];
    else if (t < 128)  W3s[t - 112]  = bwW3[et * 16 + (t - 112)];
    else if (t == 128) b3sh[0]       = bwb3[et];
    for (int idx = t; idx < 512; idx += 256)
        W2s[idx] = bwW2[et * 512 + idx];
    __syncthreads();

    int e   = blockIdx.x * 256 + t;
    int src = ei[(et * 2 + 0) * EE + e];
    int dst = ei[(et * 2 + 1) * EE + e];
    float sb = bws[et * NN + src];
    float db = bws[(1 - et) * NN + dst];

    float h1[32];
    #pragma unroll
    for (int j = 0; j < 32; j++){
        float v = sb * W1s[j] + db * W1s[32 + j] + b1sh[j];
        h1[j] = v > 0.0f ? v : 0.0f;
    }
    float h2[16];
    #pragma unroll
    for (int k = 0; k < 16; k++) h2[k] = b2sh[k];
    #pragma unroll
    for (int j = 0; j < 32; j++){
        float hv = h1[j];
        #pragma unroll
        for (int k = 0; k < 16; k++)
            h2[k] += hv * W2s[j * 16 + k];
    }
    float z = b3sh[0];
    #pragma unroll
    for (int k = 0; k < 16; k++){
        float hv = h2[k] > 0.0f ? h2[k] : 0.0f;
        z += hv * W3s[k];
    }
    float wv = 1.0f / (1.0f + expf(-z));
    if (sb > THRV || db > THRV) wv *= 2.0f;
    float c = ea[et * EE + e] * wv;

    crec[(long)et * EE + e] = (unsigned int)src | ((unsigned int)f2h(c) << 16);
}

// ---------------------------------------------------------------------------
// K3b: bucket scatter (pass A of the two-pass placement sort) + fused deg
// histogram (was a separate k_hist pass over ei -- bucket2 already reads dst,
// so the atomicAdd rides along; saves 6.4 MB of reads and one launch).
// Each 2048-edge block counts per-bucket in LDS, reserves a contiguous
// chunk per bucket with ONE global atomic, writes records into its chunk
// -> lines filled by a single block/XCD -> full-line evictions.
// Record: .x = finished 4B record from k_coef, .y = dst_local (0..255).
// ---------------------------------------------------------------------------
__global__ __launch_bounds__(256)
void k_bucket2(const int* ei, const unsigned int* crec, int* bcur, uint2* barr,
               int* deg)
{
    __shared__ int hist[NB];
    __shared__ int gbase[NB];
    const int t    = threadIdx.x;
    const int et   = blockIdx.y;
    const int base = blockIdx.x * 2048;

    for (int i = t; i < NB; i += 256) hist[i] = 0;
    __syncthreads();

    int dlv[8], bv[8], lv[8];
    unsigned int rv[8];
    #pragma unroll
    for (int j = 0; j < 8; j++){
        int e = base + j * 256 + t;
        bv[j] = -1;
        if (e < EE){
            int dst = ei[(et * 2 + 1) * EE + e];
            dlv[j]  = dst & 255;
            bv[j]   = dst >> 8;
            rv[j]   = crec[(long)et * EE + e];
            lv[j]   = atomicAdd(&hist[bv[j]], 1);
            atomicAdd(&deg[et * NN + dst], 1);
        }
    }
    __syncthreads();
    if (t < NB) gbase[t] = atomicAdd(&bcur[et * NB + t], hist[t]);
    __syncthreads();
    #pragma unroll
    for (int j = 0; j < 8; j++){
        if (bv[j] >= 0){
            int pos = gbase[bv[j]] + lv[j];
            uint2 r;
            r.x = rv[j];
            r.y = (unsigned int)dlv[j];
            barr[(long)(et * NB + bv[j]) * BCAP + pos] = r;
        }
    }
}

// ---------------------------------------------------------------------------
// K4a: local scan — each block scans 2048 elems (8/thread serial + 256-wide
// Hillis-Steele); writes local-exclusive values to rowptr, block total to bsum
// ---------------------------------------------------------------------------
__global__ __launch_bounds__(256)
void k_scan_local(const int* deg, int* rowptr, int* bsum)
{
    __shared__ int tsum[256];
    const int et  = blockIdx.y;
    const int blk = blockIdx.x;
    const int t   = threadIdx.x;
    const int base = blk * 2048 + t * 8;

    int v[8];
    int run = 0;
    #pragma unroll
    for (int j = 0; j < 8; j++){
        int i = base + j;
        int d = (i < NN) ? deg[et * NN + i] : 0;
        v[j] = run;            // thread-local exclusive prefix
        run += d;
    }
    tsum[t] = run;
    __syncthreads();
    #pragma unroll
    for (int off = 1; off < 256; off <<= 1){
        int a = (t >= off) ? tsum[t - off] : 0;
        __syncthreads();
        tsum[t] += a;
        __syncthreads();
    }
    int excl = tsum[t] - run;   // exclusive prefix of this thread within block
    #pragma unroll
    for (int j = 0; j < 8; j++){
        int i = base + j;
        if (i < NN) rowptr[et * NN + i] = excl + v[j];
    }
    if (t == 255) bsum[et * SCAN_BLK + blk] = tsum[255];
}

// ---------------------------------------------------------------------------
// K4b: scan the 25 block sums per et (trivial, 1 block, 2 active threads)
// ---------------------------------------------------------------------------
__global__ __launch_bounds__(64)
void k_scan_bsum(int* bsum, int* boff)
{
    int et = threadIdx.x;
    if (et < 2){
        int run = 0;
        for (int b = 0; b < SCAN_BLK; b++){
            int d = bsum[et * SCAN_BLK + b];
            boff[et * SCAN_BLK + b] = run;
            run += d;
        }
    }
}

// ---------------------------------------------------------------------------
// K4c: add block offsets; emit final rowptr (coalesced)
// ---------------------------------------------------------------------------
__global__ __launch_bounds__(256)
void k_scan_add(int* rowptr, const int* boff)
{
    const int et  = blockIdx.y;
    const int blk = blockIdx.x;
    const int t   = threadIdx.x;
    const int off = boff[et * SCAN_BLK + blk];
    #pragma unroll
    for (int j = 0; j < 8; j++){
        int i = blk * 2048 + j * 256 + t;
        if (i < NN)
            rowptr[et * NN + i] += off;
    }
}

// ---------------------------------------------------------------------------
// K5: pass B of the sort — pure placement, NO MLP (body is ~6 instructions,
// nothing for LICM to hoist). One block per (et,bucket); LDS cursors from
// rowptr; the bucket's epair region is contiguous and block-exclusive ->
// full-line writes.
// ---------------------------------------------------------------------------
__global__ __launch_bounds__(256)
void k_sortb(const uint2* barr, const int* bcur, const int* rowptr,
             unsigned int* epair)
{
    __shared__ int curs[256];
    const int t    = threadIdx.x;
    const int b    = blockIdx.x;
    const int et   = blockIdx.y;
    const int dst0 = b * 256;

    {
        int d = dst0 + t;
        if (d < NN) curs[t] = rowptr[et * NN + d];
    }
    __syncthreads();

    const int cnt = bcur[et * NB + b];
    const uint2* bb = barr + (long)(et * NB + b) * BCAP;

    for (int r = t; r < cnt; r += 256){
        uint2 rec = bb[r];
        int pos = atomicAdd(&curs[rec.y], 1);
        epair[(long)et * EE + pos] = rec.x;
    }
}

// ---------------------------------------------------------------------------
// K6: CSR gather — one wave per dst node, 2 dims per lane, fp32 registers.
// Predicated unroll-8: 8 independent tws-row loads in flight per wave.
// Records are 4B (src u16 | coef fp16); tail slots clamp to record 0 with
// the coef bits masked to 0, branch-free inner loop.
// ---------------------------------------------------------------------------
__global__ __launch_bounds__(256)
void k_gather(const int* rowptr, const int* deg,
              const unsigned int* epair, const u16* tws, float* agg)
{
    const int et   = blockIdx.y;
    const int w    = threadIdx.x >> 6;
    const int lane = threadIdx.x & 63;
    const int n    = blockIdx.x * 4 + w;          // 12500*4 = 50000 exactly

    int start = rowptr[et * NN + n];
    int cnt   = deg[et * NN + n];
    const unsigned int* ep = epair + (long)et * EE + start;
    const u16* tbase = tws + (long)et * NN * DD + lane * 2;

    float a0 = 0.0f, a1 = 0.0f;
    for (int k = 0; k < cnt; k += 8){
        unsigned int q[8];
        #pragma unroll
        for (int u = 0; u < 8; u++){
            int idx = k + u;
            q[u] = ep[idx < cnt ? idx : 0];
            if (idx >= cnt) q[u] &= 0xffffu;      // coef bits := 0 for tail
        }
        unsigned int pv[8];
        #pragma unroll
        for (int u = 0; u < 8; u++)
            pv[u] = *(const unsigned int*)(tbase + (long)(q[u] & 0xffffu) * DD);
        #pragma unroll
        for (int u = 0; u < 8; u++){
            float c = h2f((u16)(q[u] >> 16));
            a0 += bf2f((u16)(pv[u] & 0xffffu)) * c;
            a1 += bf2f((u16)(pv[u] >> 16)) * c;
        }
    }
    float* op = agg + ((long)(1 - et) * NN + n) * DD + lane * 2;
    op[0] = a0;
    op[1] = a1;
}

// ---------------------------------------------------------------------------
// K7: U = agg + x; z = U@nuW + nub; LayerNorm; relu -> out fp32
// (fp32 vector math UNCHANGED -- the round-10 MFMA port failed absmax
// nondeterministically (468 vs 0.137 across runs); quarantined.)
// This round: inner loop reads Us via float4 (ds_read_b128, 4 k's/load),
// same FMA accumulation order -> bit-identical results. 528B row stride
// puts the 4 tr-rows of a wave on disjoint bank groups -> ~0 conflicts
// (was 450K). kk-unroll groups 8 W-loads per region for L2 latency hiding.
// ---------------------------------------------------------------------------
__global__ __launch_bounds__(256)
void k_final(const float* agg, const float* x,
             const float* nuW, const float* nub,
             const float* lng, const float* lnb,
             float* out)
{
    __shared__ __align__(16) float Us[64 * 132];
    __shared__ float nubs[128], lngs[128], lnbs[128];

    const int t  = threadIdx.x;
    const int et = blockIdx.y;
    const int R0 = blockIdx.x * 64;
    const int rowsLeft = NN - R0;

    {   // coalesced float4 staging of U = agg + x
        const float* xb = x   + ((long)et * NN + R0) * DD;
        const float* ab = agg + ((long)et * NN + R0) * DD;
        #pragma unroll
        for (int i = 0; i < 8; i++){
            int idx = i * 256 + t;
            int row = idx >> 5;
            int c4  = (idx & 31) << 2;
            float4 v = make_float4(0.f, 0.f, 0.f, 0.f);
            if (row < rowsLeft){
                float4 xv4 = *(const float4*)(xb + row * DD + c4);
                float4 av4 = *(const float4*)(ab + row * DD + c4);
                v.x = xv4.x + av4.x; v.y = xv4.y + av4.y;
                v.z = xv4.z + av4.z; v.w = xv4.w + av4.w;
            }
            *(float4*)&Us[row * 132 + c4] = v;
        }
    }
    if (t < 128) nubs[t] = nub[et * 128 + t];
    else {
        lngs[t - 128] = lng[et * 128 + (t - 128)];
        lnbs[t - 128] = lnb[et * 128 + (t - 128)];
    }
    __syncthreads();

    const int tc = t & 15, tr = t >> 4;
    const float* Wg = nuW + et * 16384;    // [128][128], L2-resident
    float acc[4][8];
    for (int m = 0; m < 4; m++)
        for (int j = 0; j < 8; j++) acc[m][j] = 0.0f;
    for (int k4 = 0; k4 < 32; k4++){
        // one ds_read_b128 per m: 4 k-values (16B-aligned: 528*row + 16*k4)
        float xv[4][4];
        #pragma unroll
        for (int m = 0; m < 4; m++){
            float4 q = *(const float4*)&Us[(tr + 16 * m) * 132 + k4 * 4];
            xv[m][0] = q.x; xv[m][1] = q.y; xv[m][2] = q.z; xv[m][3] = q.w;
        }
        #pragma unroll
        for (int kk = 0; kk < 4; kk++){
            int k = k4 * 4 + kk;
            float4 wv0 = *(const float4*)(Wg + k * 128 + tc * 8);
            float4 wv1 = *(const float4*)(Wg + k * 128 + tc * 8 + 4);
            #pragma unroll
            for (int m = 0; m < 4; m++){
                float xm = xv[m][kk];
                acc[m][0] += xm * wv0.x; acc[m][1] += xm * wv0.y;
                acc[m][2] += xm * wv0.z; acc[m][3] += xm * wv0.w;
                acc[m][4] += xm * wv1.x; acc[m][5] += xm * wv1.y;
                acc[m][6] += xm * wv1.z; acc[m][7] += xm * wv1.w;
            }
        }
    }

    // z = acc + nub; in-register LayerNorm per row (16 tc-lanes hold a row)
    for (int m = 0; m < 4; m++){
        float z[8];
        float s = 0.0f, ss = 0.0f;
        #pragma unroll
        for (int j = 0; j < 8; j++){
            z[j] = acc[m][j] + nubs[tc * 8 + j];
            s += z[j]; ss += z[j] * z[j];
        }
        s  += __shfl_xor(s, 1);  s  += __shfl_xor(s, 2);
        s  += __shfl_xor(s, 4);  s  += __shfl_xor(s, 8);
        ss += __shfl_xor(ss, 1); ss += __shfl_xor(ss, 2);
        ss += __shfl_xor(ss, 4); ss += __shfl_xor(ss, 8);
        float mean = s * (1.0f / 128.0f);
        float var  = ss * (1.0f / 128.0f) - mean * mean;
        float rstd = rsqrtf(var + 1e-5f);
        int grow = R0 + tr + 16 * m;
        if (grow < NN){
            float4 o0, o1;
            float o[8];
            #pragma unroll
            for (int j = 0; j < 8; j++){
                int col = tc * 8 + j;
                float v = (z[j] - mean) * rstd * lngs[col] + lnbs[col];
                o[j] = v > 0.0f ? v : 0.0f;
            }
            o0.x = o[0]; o0.y = o[1]; o0.z = o[2]; o0.w = o[3];
            o1.x = o[4]; o1.y = o[5]; o1.z = o[6]; o1.w = o[7];
            float* op = out + ((long)et * NN + grow) * DD + tc * 8;
            *(float4*)(op)     = o0;
            *(float4*)(op + 4) = o1;
        }
    }
}

// ---------------------------------------------------------------------------
extern "C" void kernel_launch(void* const* d_in, const int* in_sizes, int n_in,
                              void* d_out, int out_size, void* d_ws, size_t ws_size,
                              hipStream_t stream)
{
    const float* x    = (const float*)d_in[0];
    const int*   ei   = (const int*)d_in[1];
    const float* ea   = (const float*)d_in[2];
    const float* bdW1 = (const float*)d_in[3];
    const float* bdb1 = (const float*)d_in[4];
    const float* bdW2 = (const float*)d_in[5];
    const float* bdb2 = (const float*)d_in[6];
    const float* bdW3 = (const float*)d_in[7];
    const float* bdb3 = (const float*)d_in[8];
    const float* etW1 = (const float*)d_in[9];
    const float* etb1 = (const float*)d_in[10];
    const float* etW2 = (const float*)d_in[11];
    const float* etb2 = (const float*)d_in[12];
    const float* bwW1 = (const float*)d_in[13];
    const float* bwb1 = (const float*)d_in[14];
    const float* bwW2 = (const float*)d_in[15];
    const float* bwb2 = (const float*)d_in[16];
    const float* bwW3 = (const float*)d_in[17];
    const float* bwb3 = (const float*)d_in[18];
    const float* nuW  = (const float*)d_in[19];
    const float* nub  = (const float*)d_in[20];
    const float* lng  = (const float*)d_in[21];
    const float* lnb  = (const float*)d_in[22];

    // workspace layout (bytes):
    //   agg    [2*N*128] f32 : 51,200,000   @ 0
    //     aliased (both dead before k_gather overwrites all of agg):
    //       barr [2*NB*BCAP] uint2 = 16,056,320  @ 0
    //       crec [2*E]       u32   =  6,400,000  @ 17,000,000
    //   tws    [2*N*128] bf16: 25,600,000   @ 51,200,000
    //   bws    [2*N]     f32 :    400,000   @ 76,800,000
    //   deg    [2*N]     i32 :    400,000   @ 77,200,000
    //   bcur   [2*NB]    i32 :      1,568   @ 77,600,000   (zeroed with deg)
    //   rowptr [2*N]     i32 :    400,000   @ 77,602,048
    //   epair  [2*E]     u32 :  6,400,000   @ 78,002,048
    //   bsum   [2*25]    i32 :        200   @ 84,402,048
    //   boff   [2*25]    i32 :        200   @ 84,402,560
    char*  wsb    = (char*)d_ws;
    float* agg    = (float*)(wsb);
    uint2* barr   = (uint2*)(wsb);
    unsigned int* crec = (unsigned int*)(wsb + 17000000L);
    u16*   tws    = (u16*)  (wsb + 51200000L);
    float* bws    = (float*)(wsb + 76800000L);
    int*   deg    = (int*)  (wsb + 77200000L);
    int*   bcur   = (int*)  (wsb + 77600000L);
    int*   rowptr = (int*)  (wsb + 77602048L);
    unsigned int* epair = (unsigned int*)(wsb + 78002048L);
    int*   bsum   = (int*)  (wsb + 84402048L);
    int*   boff   = (int*)  (wsb + 84402560L);

    dim3 blk(256);
    // zero deg (2*NN) and bcur (2*NB) in one contiguous pass
    k_zero<<<dim3((2 * NN + 2 * NB + 255) / 256 + 1), blk, 0, stream>>>(deg, 2 * NN + 512);

    dim3 g1((NN + 63) / 64, 2);
    k_boundary <<<g1, blk, 0, stream>>>(x, bdW1, bdb1, bdW2, bdb2, bdW3, bdb3, bws);
    k_edgetrans<<<g1, blk, 0, stream>>>(x, etW1, etb1, etW2, etb2, tws);

    dim3 ge(EE / 256, 2);    // 800000/256 = 3125 exactly
    k_coef<<<ge, blk, 0, stream>>>(ei, ea, bwW1, bwb1, bwW2, bwb2, bwW3, bwb3,
                                   bws, crec);

    dim3 gb((EE + 2047) / 2048, 2);   // 391 blocks, 2048 edges each
    k_bucket2<<<gb, blk, 0, stream>>>(ei, crec, bcur, barr, deg);

    dim3 gs(SCAN_BLK, 2);
    k_scan_local<<<gs, blk, 0, stream>>>(deg, rowptr, bsum);
    k_scan_bsum <<<dim3(1), dim3(64), 0, stream>>>(bsum, boff);
    k_scan_add  <<<gs, blk, 0, stream>>>(rowptr, boff);

    dim3 gp(NB, 2);   // one block per (et, bucket)
    k_sortb<<<gp, blk, 0, stream>>>(barr, bcur, rowptr, epair);

    k_gather<<<dim3(NN / 4, 2), blk, 0, stream>>>(rowptr, deg, epair, tws, agg);

    k_final<<<g1, blk, 0, stream>>>(agg, x, nuW, nub, lng, lnb, (float*)d_out);
}

// Round 14
// 465.617 us; speedup vs baseline: 1.1475x; 1.1243x over previous
//
#include <hip/hip_runtime.h>

#define NN 50000
#define DD 128
#define EE 800000
#define THRV 0.3f
#define SCAN_BLK 25           // ceil(50000 / 2048)
#define NB 196                // ceil(50000 / 256) dst-buckets of 256 nodes
#define BCAP 5120             // bucket capacity; mean 4096, sigma ~64 -> 16 sigma

typedef unsigned short u16;
typedef _Float16 f16x8 __attribute__((ext_vector_type(8)));
typedef float    f32x4 __attribute__((ext_vector_type(4)));

__device__ __forceinline__ float bf2f(u16 u){
    union { unsigned int i; float f; } v; v.i = ((unsigned int)u) << 16; return v.f;
}
__device__ __forceinline__ u16 f2bf(float f){
    unsigned int x = __float_as_uint(f);
    unsigned int r = (x + 0x7fffu + ((x >> 16) & 1u)) >> 16;
    return (u16)r;
}
__device__ __forceinline__ u16 f2h(float f){
    union { _Float16 h; u16 u; } v; v.h = (_Float16)f; return v.u;
}
__device__ __forceinline__ float h2f(u16 u){
    union { _Float16 h; u16 u; } v; v.u = u; return (float)v.h;
}

// ---------------------------------------------------------------------------
// K0: zero bucket cursors (deg no longer needs zeroing -- k_deg overwrites it)
// ---------------------------------------------------------------------------
__global__ __launch_bounds__(256)
void k_zero(int* p, int n)
{
    int i = blockIdx.x * 256 + threadIdx.x;
    if (i < n) p[i] = 0;
}

// ---------------------------------------------------------------------------
// K1: boundary MLP via MFMA.  b = sigmoid(relu(relu(x@W1+b1)@W2+b2)@W3+b3)
// (round-9 verified: 85us fp32 -> out of top-5; absmax unchanged)
// m89 layouts: A: lane l = A[l&15][(l>>4)*8..+7]; B: lane l = B[(l>>4)*8..+7][l&15]
// (W staged TRANSPOSED); C/D: col=lane&15, row=(lane>>4)*4+reg.
// ---------------------------------------------------------------------------
__global__ __launch_bounds__(256)
void k_boundary(const float* x,
                const float* bdW1, const float* bdb1,
                const float* bdW2, const float* bdb2,
                const float* bdW3, const float* bdb3,
                float* bws)
{
    __shared__ __align__(16) _Float16 Xh[64][136];
    __shared__ __align__(16) char wbuf[17408];   // W1t[64][136]; later Bh1[64][72] @0 + W2t[32][72] @9216
    __shared__ float b1s[64];
    __shared__ float b2s[32];
    __shared__ float W3s[32];
    __shared__ float b3s[1];

    _Float16 (*W1t)[136] = (_Float16(*)[136])wbuf;
    _Float16 (*Bh1)[72]  = (_Float16(*)[72])wbuf;
    _Float16 (*W2t)[72]  = (_Float16(*)[72])(wbuf + 9216);

    const int t    = threadIdx.x;
    const int et   = blockIdx.y;
    const int R0   = blockIdx.x * 64;
    const int rowsLeft = NN - R0;
    const int w    = t >> 6;
    const int lane = t & 63;
    const int lc   = lane & 15;
    const int lk   = (lane >> 4) << 3;
    const int arow = (w << 4) + lc;
    const int hrow0 = (w << 4) + ((lane >> 4) << 2);

    {   // stage X -> f16 (coalesced float4 reads)
        const float* xb = x + ((long)et * NN + R0) * DD;
        #pragma unroll
        for (int i = 0; i < 8; i++){
            int idx = i * 256 + t;
            int row = idx >> 5;
            int c4  = (idx & 31) << 2;
            float4 v = make_float4(0.f, 0.f, 0.f, 0.f);
            if (row < rowsLeft) v = *(const float4*)(xb + row * DD + c4);
            union { _Float16 h[4]; uint2 u; } pk;
            pk.h[0] = (_Float16)v.x; pk.h[1] = (_Float16)v.y;
            pk.h[2] = (_Float16)v.z; pk.h[3] = (_Float16)v.w;
            *(uint2*)&Xh[row][c4] = pk.u;
        }
    }
    {   // stage W1^T: bdW1 [128][64] -> W1t[n][k] f16 (2048 float4)
        const float* Wg = bdW1 + et * 8192;
        #pragma unroll
        for (int i = 0; i < 8; i++){
            int idx = i * 256 + t;
            int k   = idx >> 4;
            int n4  = (idx & 15) << 2;
            float4 wv = *(const float4*)(Wg + k * 64 + n4);
            W1t[n4 + 0][k] = (_Float16)wv.x;
            W1t[n4 + 1][k] = (_Float16)wv.y;
            W1t[n4 + 2][k] = (_Float16)wv.z;
            W1t[n4 + 3][k] = (_Float16)wv.w;
        }
    }
    if (t < 64)        b1s[t]      = bdb1[et * 64 + t];
    else if (t < 96)   b2s[t - 64] = bdb2[et * 32 + (t - 64)];
    else if (t < 128)  W3s[t - 96] = bdW3[et * 32 + (t - 96)];
    else if (t == 128) b3s[0]      = bdb3[et];
    __syncthreads();

    // GEMM1: h1 = X @ W1   [64x64], K=128
    f32x4 acc[4];
    #pragma unroll
    for (int nt = 0; nt < 4; nt++) acc[nt] = (f32x4){0.f, 0.f, 0.f, 0.f};
    #pragma unroll
    for (int s = 0; s < 4; s++){
        f16x8 af = *(const f16x8*)&Xh[arow][s * 32 + lk];
        #pragma unroll
        for (int nt = 0; nt < 4; nt++){
            f16x8 bf = *(const f16x8*)&W1t[nt * 16 + lc][s * 32 + lk];
            acc[nt] = __builtin_amdgcn_mfma_f32_16x16x32_f16(af, bf, acc[nt], 0, 0, 0);
        }
    }
    __syncthreads();   // W1t reads done; Bh1 aliases its space

    // Bh1 = relu(acc + b1) -> f16  (D layout scalar stores)
    #pragma unroll
    for (int nt = 0; nt < 4; nt++){
        int col = nt * 16 + lc;
        float bias = b1s[col];
        #pragma unroll
        for (int r = 0; r < 4; r++){
            float v = acc[nt][r] + bias;
            Bh1[hrow0 + r][col] = (_Float16)(v > 0.f ? v : 0.f);
        }
    }
    {   // stage W2^T: bdW2 [64][32] -> W2t[n][k] f16 (512 float4)
        const float* Wg = bdW2 + et * 2048;
        #pragma unroll
        for (int i = 0; i < 2; i++){
            int idx = i * 256 + t;
            int k   = idx >> 3;
            int n4  = (idx & 7) << 2;
            float4 wv = *(const float4*)(Wg + k * 32 + n4);
            W2t[n4 + 0][k] = (_Float16)wv.x;
            W2t[n4 + 1][k] = (_Float16)wv.y;
            W2t[n4 + 2][k] = (_Float16)wv.z;
            W2t[n4 + 3][k] = (_Float16)wv.w;
        }
    }
    __syncthreads();

    // GEMM2: h2 = h1 @ W2   [64x32], K=64
    f32x4 acc2[2];
    acc2[0] = (f32x4){0.f, 0.f, 0.f, 0.f};
    acc2[1] = (f32x4){0.f, 0.f, 0.f, 0.f};
    #pragma unroll
    for (int s = 0; s < 2; s++){
        f16x8 af = *(const f16x8*)&Bh1[arow][s * 32 + lk];
        #pragma unroll
        for (int nt = 0; nt < 2; nt++){
            f16x8 bf = *(const f16x8*)&W2t[nt * 16 + lc][s * 32 + lk];
            acc2[nt] = __builtin_amdgcn_mfma_f32_16x16x32_f16(af, bf, acc2[nt], 0, 0, 0);
        }
    }

    // phase 3 in-register: per-row dot32(relu(h2+b2), W3) via lane-group reduce.
    float part[4];
    #pragma unroll
    for (int r = 0; r < 4; r++){
        float p = 0.f;
        #pragma unroll
        for (int nt = 0; nt < 2; nt++){
            int col = nt * 16 + lc;
            float v = acc2[nt][r] + b2s[col];
            v = v > 0.f ? v : 0.f;
            p += v * W3s[col];
        }
        part[r] = p;
    }
    #pragma unroll
    for (int r = 0; r < 4; r++){
        part[r] += __shfl_xor(part[r], 1);
        part[r] += __shfl_xor(part[r], 2);
        part[r] += __shfl_xor(part[r], 4);
        part[r] += __shfl_xor(part[r], 8);
    }
    if (lc == 0){
        #pragma unroll
        for (int r = 0; r < 4; r++){
            int row = R0 + hrow0 + r;
            if (row < NN){
                float b = 1.0f / (1.0f + expf(-(part[r] + b3s[0])));
                bws[et * NN + row] = b;
            }
        }
    }
}

// ---------------------------------------------------------------------------
// K2: edge transform  t = relu(x@W1+b1)@W2+b2  -> bf16 [2,N,128]  via MFMA.
// (round-8 verified: 127.8us fp32 -> <84us; absmax unchanged)
// ---------------------------------------------------------------------------
__global__ __launch_bounds__(256)
void k_edgetrans(const float* x,
                 const float* etW1, const float* etb1,
                 const float* etW2, const float* etb2,
                 u16* tws)
{
    __shared__ __align__(16) _Float16 Ah[64][136];   // X (f16), then H
    __shared__ __align__(16) _Float16 Wt[128][136];  // W1^T, then W2^T
    __shared__ float b1s[128];
    __shared__ float b2s[128];

    const int t    = threadIdx.x;
    const int et   = blockIdx.y;
    const int R0   = blockIdx.x * 64;
    const int rowsLeft = NN - R0;
    const int w    = t >> 6;
    const int lane = t & 63;
    const int lc   = lane & 15;          // col-within-tile / A-row offset
    const int lk   = (lane >> 4) << 3;   // k-group base: 0,8,16,24
    const int arow = (w << 4) + lc;      // this lane's A row (0..63)

    {   // stage X -> f16 (coalesced float4 reads, 8B LDS writes)
        const float* xb = x + ((long)et * NN + R0) * DD;
        #pragma unroll
        for (int i = 0; i < 8; i++){
            int idx = i * 256 + t;
            int row = idx >> 5;
            int c4  = (idx & 31) << 2;
            float4 v = make_float4(0.f, 0.f, 0.f, 0.f);
            if (row < rowsLeft) v = *(const float4*)(xb + row * DD + c4);
            union { _Float16 h[4]; uint2 u; } pk;
            pk.h[0] = (_Float16)v.x; pk.h[1] = (_Float16)v.y;
            pk.h[2] = (_Float16)v.z; pk.h[3] = (_Float16)v.w;
            *(uint2*)&Ah[row][c4] = pk.u;
        }
    }
    {   // stage W1 transposed -> f16
        const float* Wg = etW1 + et * 16384;
        #pragma unroll
        for (int i = 0; i < 16; i++){
            int idx = i * 256 + t;
            int k   = idx >> 5;
            int n4  = (idx & 31) << 2;
            float4 wv = *(const float4*)(Wg + k * 128 + n4);
            Wt[n4 + 0][k] = (_Float16)wv.x;
            Wt[n4 + 1][k] = (_Float16)wv.y;
            Wt[n4 + 2][k] = (_Float16)wv.z;
            Wt[n4 + 3][k] = (_Float16)wv.w;
        }
    }
    if (t < 128) b1s[t] = etb1[et * 128 + t];
    else         b2s[t - 128] = etb2[et * 128 + (t - 128)];
    __syncthreads();

    // GEMM1: h = X @ W1  (acc in fp32)
    f32x4 acc[8];
    #pragma unroll
    for (int nt = 0; nt < 8; nt++) acc[nt] = (f32x4){0.f, 0.f, 0.f, 0.f};
    #pragma unroll
    for (int s = 0; s < 4; s++){
        f16x8 af = *(const f16x8*)&Ah[arow][s * 32 + lk];
        #pragma unroll
        for (int nt = 0; nt < 8; nt++){
            f16x8 bf = *(const f16x8*)&Wt[nt * 16 + lc][s * 32 + lk];
            acc[nt] = __builtin_amdgcn_mfma_f32_16x16x32_f16(af, bf, acc[nt], 0, 0, 0);
        }
    }
    __syncthreads();   // all GEMM1 LDS reads done before overwriting Ah/Wt

    // H = relu(acc + b1) -> f16 into Ah (D layout: col=lane&15, row=(lane>>4)*4+r)
    {
        const int hrow0 = (w << 4) + ((lane >> 4) << 2);
        #pragma unroll
        for (int nt = 0; nt < 8; nt++){
            int col = nt * 16 + lc;
            float bias = b1s[col];
            #pragma unroll
            for (int r = 0; r < 4; r++){
                float v = acc[nt][r] + bias;
                Ah[hrow0 + r][col] = (_Float16)(v > 0.f ? v : 0.f);
            }
        }
    }
    {   // stage W2 transposed -> f16 (over W1)
        const float* Wg = etW2 + et * 16384;
        #pragma unroll
        for (int i = 0; i < 16; i++){
            int idx = i * 256 + t;
            int k   = idx >> 5;
            int n4  = (idx & 31) << 2;
            float4 wv = *(const float4*)(Wg + k * 128 + n4);
            Wt[n4 + 0][k] = (_Float16)wv.x;
            Wt[n4 + 1][k] = (_Float16)wv.y;
            Wt[n4 + 2][k] = (_Float16)wv.z;
            Wt[n4 + 3][k] = (_Float16)wv.w;
        }
    }
    __syncthreads();

    // GEMM2: t = H @ W2
    f32x4 acc2[8];
    #pragma unroll
    for (int nt = 0; nt < 8; nt++) acc2[nt] = (f32x4){0.f, 0.f, 0.f, 0.f};
    #pragma unroll
    for (int s = 0; s < 4; s++){
        f16x8 af = *(const f16x8*)&Ah[arow][s * 32 + lk];
        #pragma unroll
        for (int nt = 0; nt < 8; nt++){
            f16x8 bf = *(const f16x8*)&Wt[nt * 16 + lc][s * 32 + lk];
            acc2[nt] = __builtin_amdgcn_mfma_f32_16x16x32_f16(af, bf, acc2[nt], 0, 0, 0);
        }
    }

    // store t + b2 as bf16 (D layout scalar stores; block region is contiguous
    // so L2 assembles full lines)
    {
        const int hrow0 = (w << 4) + ((lane >> 4) << 2);
        #pragma unroll
        for (int nt = 0; nt < 8; nt++){
            int col = nt * 16 + lc;
            float bias = b2s[col];
            #pragma unroll
            for (int r = 0; r < 4; r++){
                int grow = R0 + hrow0 + r;
                if (grow < NN)
                    tws[((long)et * NN + grow) * DD + col] = f2bf(acc2[nt][r] + bias);
            }
        }
    }
}

// ---------------------------------------------------------------------------
// K3a: per-edge coefficient MLP, COALESCED output (no scatter).
// One edge per thread, STRAIGHT-LINE MLP -- never put this MLP in a loop:
// LICM hoists the loop-invariant LDS weight reads into registers, hits the
// 256-VGPR cap, and spills h1/h2 to scratch (round 4/6: 630 MB scratch
// FETCH, 517 us; #pragma unroll 1 does NOT prevent it). This straight-line
// form measured 60-72 VGPR in rounds 0-3.
// Output record: src | f2h(ea*coef)<<16, written to crec[et*EE+e].
// ---------------------------------------------------------------------------
__global__ __launch_bounds__(256)
void k_coef(const int* ei, const float* ea,
            const float* bwW1, const float* bwb1,
            const float* bwW2, const float* bwb2,
            const float* bwW3, const float* bwb3,
            const float* bws,
            unsigned int* crec)
{
    __shared__ float W1s[64];
    __shared__ float b1sh[32];
    __shared__ float W2s[512];
    __shared__ float b2sh[16];
    __shared__ float W3s[16];
    __shared__ float b3sh[1];
    const int t  = threadIdx.x;
    const int et = blockIdx.y;

    if (t < 64)        W1s[t]        = bwW1[et * 64 + t];
    else if (t < 96)   b1sh[t - 64]  = bwb1[et * 32 + (t - 64)];
    else if (t < 112)  b2sh[t - 96]  = bwb2[et * 16 + (t - 96)];
    else if (t < 128)  W3s[t - 112]  = bwW3[et * 16 + (t - 112)];
    else if (t == 128) b3sh[0]       = bwb3[et];
    for (int idx = t; idx < 512; idx += 256)
        W2s[idx] = bwW2[et * 512 + idx];
    __syncthreads();

    int e   = blockIdx.x * 256 + t;
    int src = ei[(et * 2 + 0) * EE + e];
    int dst = ei[(et * 2 + 1) * EE + e];
    float sb = bws[et * NN + src];
    float db = bws[(1 - et) * NN + dst];

    float h1[32];
    #pragma unroll
    for (int j = 0; j < 32; j++){
        float v = sb * W1s[j] + db * W1s[32 + j] + b1sh[j];
        h1[j] = v > 0.0f ? v : 0.0f;
    }
    float h2[16];
    #pragma unroll
    for (int k = 0; k < 16; k++) h2[k] = b2sh[k];
    #pragma unroll
    for (int j = 0; j < 32; j++){
        float hv = h1[j];
        #pragma unroll
        for (int k = 0; k < 16; k++)
            h2[k] += hv * W2s[j * 16 + k];
    }
    float z = b3sh[0];
    #pragma unroll
    for (int k = 0; k < 16; k++){
        float hv = h2[k] > 0.0f ? h2[k] : 0.0f;
        z += hv * W3s[k];
    }
    float wv = 1.0f / (1.0f + expf(-z));
    if (sb > THRV || db > THRV) wv *= 2.0f;
    float c = ea[et * EE + e] * wv;

    crec[(long)et * EE + e] = (unsigned int)src | ((unsigned int)f2h(c) << 16);
}

// ---------------------------------------------------------------------------
// K3b: bucket scatter (pass A of the two-pass placement sort).
// NO deg atomics (round-12 fusion REGRESSED: 1.6M cross-XCD atomics ping-
// ponged dirty lines between per-XCD L2s -> WRITE_SIZE 70 MB, 85 us; deg is
// now derived from the bucket data by k_deg with zero global atomics).
// 512 threads x 8 edges = 4096 edges/block: per-bucket chunks ~167 B (was
// 84 B) -> less partial-line waste, half the gbase atomics.
// Record: .x = finished 4B record from k_coef, .y = dst_local (0..255).
// ---------------------------------------------------------------------------
__global__ __launch_bounds__(512)
void k_bucket2(const int* ei, const unsigned int* crec, int* bcur, uint2* barr)
{
    __shared__ int hist[NB];
    __shared__ int gbase[NB];
    const int t    = threadIdx.x;
    const int et   = blockIdx.y;
    const int base = blockIdx.x * 4096;

    for (int i = t; i < NB; i += 512) hist[i] = 0;
    __syncthreads();

    int dlv[8], bv[8], lv[8];
    unsigned int rv[8];
    #pragma unroll
    for (int j = 0; j < 8; j++){
        int e = base + j * 512 + t;
        bv[j] = -1;
        if (e < EE){
            int dst = ei[(et * 2 + 1) * EE + e];
            dlv[j]  = dst & 255;
            bv[j]   = dst >> 8;
            rv[j]   = crec[(long)et * EE + e];
            lv[j]   = atomicAdd(&hist[bv[j]], 1);
        }
    }
    __syncthreads();
    if (t < NB) gbase[t] = atomicAdd(&bcur[et * NB + t], hist[t]);
    __syncthreads();
    #pragma unroll
    for (int j = 0; j < 8; j++){
        if (bv[j] >= 0){
            int pos = gbase[bv[j]] + lv[j];
            uint2 r;
            r.x = rv[j];
            r.y = (unsigned int)dlv[j];
            barr[(long)(et * NB + bv[j]) * BCAP + pos] = r;
        }
    }
}

// ---------------------------------------------------------------------------
// K3c: derive deg from bucket data -- one block per (et,bucket), LDS
// histogram of dst_local over the bucket's records (L2-hot, just written),
// coalesced deg write. Replaces 1.6M global atomics with LDS atomics.
// ---------------------------------------------------------------------------
__global__ __launch_bounds__(256)
void k_deg(const uint2* barr, const int* bcur, int* deg)
{
    __shared__ int cnt[256];
    const int t  = threadIdx.x;
    const int b  = blockIdx.x;
    const int et = blockIdx.y;
    cnt[t] = 0;
    __syncthreads();
    const int n = bcur[et * NB + b];
    const uint2* bb = barr + (long)(et * NB + b) * BCAP;
    for (int r = t; r < n; r += 256)
        atomicAdd(&cnt[bb[r].y], 1);
    __syncthreads();
    int d = b * 256 + t;
    if (d < NN) deg[et * NN + d] = cnt[t];
}

// ---------------------------------------------------------------------------
// K4a: local scan — each block scans 2048 elems (8/thread serial + 256-wide
// Hillis-Steele); writes local-exclusive values to rowptr, block total to bsum
// ---------------------------------------------------------------------------
__global__ __launch_bounds__(256)
void k_scan_local(const int* deg, int* rowptr, int* bsum)
{
    __shared__ int tsum[256];
    const int et  = blockIdx.y;
    const int blk = blockIdx.x;
    const int t   = threadIdx.x;
    const int base = blk * 2048 + t * 8;

    int v[8];
    int run = 0;
    #pragma unroll
    for (int j = 0; j < 8; j++){
        int i = base + j;
        int d = (i < NN) ? deg[et * NN + i] : 0;
        v[j] = run;            // thread-local exclusive prefix
        run += d;
    }
    tsum[t] = run;
    __syncthreads();
    #pragma unroll
    for (int off = 1; off < 256; off <<= 1){
        int a = (t >= off) ? tsum[t - off] : 0;
        __syncthreads();
        tsum[t] += a;
        __syncthreads();
    }
    int excl = tsum[t] - run;   // exclusive prefix of this thread within block
    #pragma unroll
    for (int j = 0; j < 8; j++){
        int i = base + j;
        if (i < NN) rowptr[et * NN + i] = excl + v[j];
    }
    if (t == 255) bsum[et * SCAN_BLK + blk] = tsum[255];
}

// ---------------------------------------------------------------------------
// K4b: scan the 25 block sums per et (trivial, 1 block, 2 active threads)
// ---------------------------------------------------------------------------
__global__ __launch_bounds__(64)
void k_scan_bsum(int* bsum, int* boff)
{
    int et = threadIdx.x;
    if (et < 2){
        int run = 0;
        for (int b = 0; b < SCAN_BLK; b++){
            int d = bsum[et * SCAN_BLK + b];
            boff[et * SCAN_BLK + b] = run;
            run += d;
        }
    }
}

// ---------------------------------------------------------------------------
// K4c: add block offsets; emit final rowptr (coalesced)
// ---------------------------------------------------------------------------
__global__ __launch_bounds__(256)
void k_scan_add(int* rowptr, const int* boff)
{
    const int et  = blockIdx.y;
    const int blk = blockIdx.x;
    const int t   = threadIdx.x;
    const int off = boff[et * SCAN_BLK + blk];
    #pragma unroll
    for (int j = 0; j < 8; j++){
        int i = blk * 2048 + j * 256 + t;
        if (i < NN)
            rowptr[et * NN + i] += off;
    }
}

// ---------------------------------------------------------------------------
// K5: pass B of the sort — pure placement, NO MLP (body is ~6 instructions,
// nothing for LICM to hoist). One block per (et,bucket); LDS cursors from
// rowptr; the bucket's epair region is contiguous and block-exclusive ->
// full-line writes.
// ---------------------------------------------------------------------------
__global__ __launch_bounds__(256)
void k_sortb(const uint2* barr, const int* bcur, const int* rowptr,
             unsigned int* epair)
{
    __shared__ int curs[256];
    const int t    = threadIdx.x;
    const int b    = blockIdx.x;
    const int et   = blockIdx.y;
    const int dst0 = b * 256;

    {
        int d = dst0 + t;
        if (d < NN) curs[t] = rowptr[et * NN + d];
    }
    __syncthreads();

    const int cnt = bcur[et * NB + b];
    const uint2* bb = barr + (long)(et * NB + b) * BCAP;

    for (int r = t; r < cnt; r += 256){
        uint2 rec = bb[r];
        int pos = atomicAdd(&curs[rec.y], 1);
        epair[(long)et * EE + pos] = rec.x;
    }
}

// ---------------------------------------------------------------------------
// K6: CSR gather — one wave per dst node, 2 dims per lane, fp32 registers.
// Predicated unroll-8: 8 independent tws-row loads in flight per wave.
// Records are 4B (src u16 | coef fp16); tail slots clamp to record 0 with
// the coef bits masked to 0, branch-free inner loop.
// ---------------------------------------------------------------------------
__global__ __launch_bounds__(256)
void k_gather(const int* rowptr, const int* deg,
              const unsigned int* epair, const u16* tws, float* agg)
{
    const int et   = blockIdx.y;
    const int w    = threadIdx.x >> 6;
    const int lane = threadIdx.x & 63;
    const int n    = blockIdx.x * 4 + w;          // 12500*4 = 50000 exactly

    int start = rowptr[et * NN + n];
    int cnt   = deg[et * NN + n];
    const unsigned int* ep = epair + (long)et * EE + start;
    const u16* tbase = tws + (long)et * NN * DD + lane * 2;

    float a0 = 0.0f, a1 = 0.0f;
    for (int k = 0; k < cnt; k += 8){
        unsigned int q[8];
        #pragma unroll
        for (int u = 0; u < 8; u++){
            int idx = k + u;
            q[u] = ep[idx < cnt ? idx : 0];
            if (idx >= cnt) q[u] &= 0xffffu;      // coef bits := 0 for tail
        }
        unsigned int pv[8];
        #pragma unroll
        for (int u = 0; u < 8; u++)
            pv[u] = *(const unsigned int*)(tbase + (long)(q[u] & 0xffffu) * DD);
        #pragma unroll
        for (int u = 0; u < 8; u++){
            float c = h2f((u16)(q[u] >> 16));
            a0 += bf2f((u16)(pv[u] & 0xffffu)) * c;
            a1 += bf2f((u16)(pv[u] >> 16)) * c;
        }
    }
    float* op = agg + ((long)(1 - et) * NN + n) * DD + lane * 2;
    op[0] = a0;
    op[1] = a1;
}

// ---------------------------------------------------------------------------
// K7: U = agg + x; z = U@nuW + nub; LayerNorm; relu -> out fp32
// (fp32 vector math; round-12 verified with float4 LDS reads -- left top-5.
// The round-10 MFMA port failed absmax nondeterministically; quarantined.)
// ---------------------------------------------------------------------------
__global__ __launch_bounds__(256)
void k_final(const float* agg, const float* x,
             const float* nuW, const float* nub,
             const float* lng, const float* lnb,
             float* out)
{
    __shared__ __align__(16) float Us[64 * 132];
    __shared__ float nubs[128], lngs[128], lnbs[128];

    const int t  = threadIdx.x;
    const int et = blockIdx.y;
    const int R0 = blockIdx.x * 64;
    const int rowsLeft = NN - R0;

    {   // coalesced float4 staging of U = agg + x
        const float* xb = x   + ((long)et * NN + R0) * DD;
        const float* ab = agg + ((long)et * NN + R0) * DD;
        #pragma unroll
        for (int i = 0; i < 8; i++){
            int idx = i * 256 + t;
            int row = idx >> 5;
            int c4  = (idx & 31) << 2;
            float4 v = make_float4(0.f, 0.f, 0.f, 0.f);
            if (row < rowsLeft){
                float4 xv4 = *(const float4*)(xb + row * DD + c4);
                float4 av4 = *(const float4*)(ab + row * DD + c4);
                v.x = xv4.x + av4.x; v.y = xv4.y + av4.y;
                v.z = xv4.z + av4.z; v.w = xv4.w + av4.w;
            }
            *(float4*)&Us[row * 132 + c4] = v;
        }
    }
    if (t < 128) nubs[t] = nub[et * 128 + t];
    else {
        lngs[t - 128] = lng[et * 128 + (t - 128)];
        lnbs[t - 128] = lnb[et * 128 + (t - 128)];
    }
    __syncthreads();

    const int tc = t & 15, tr = t >> 4;
    const float* Wg = nuW + et * 16384;    // [128][128], L2-resident
    float acc[4][8];
    for (int m = 0; m < 4; m++)
        for (int j = 0; j < 8; j++) acc[m][j] = 0.0f;
    for (int k4 = 0; k4 < 32; k4++){
        // one ds_read_b128 per m: 4 k-values (16B-aligned: 528*row + 16*k4)
        float xv[4][4];
        #pragma unroll
        for (int m = 0; m < 4; m++){
            float4 q = *(const float4*)&Us[(tr + 16 * m) * 132 + k4 * 4];
            xv[m][0] = q.x; xv[m][1] = q.y; xv[m][2] = q.z; xv[m][3] = q.w;
        }
        #pragma unroll
        for (int kk = 0; kk < 4; kk++){
            int k = k4 * 4 + kk;
            float4 wv0 = *(const float4*)(Wg + k * 128 + tc * 8);
            float4 wv1 = *(const float4*)(Wg + k * 128 + tc * 8 + 4);
            #pragma unroll
            for (int m = 0; m < 4; m++){
                float xm = xv[m][kk];
                acc[m][0] += xm * wv0.x; acc[m][1] += xm * wv0.y;
                acc[m][2] += xm * wv0.z; acc[m][3] += xm * wv0.w;
                acc[m][4] += xm * wv1.x; acc[m][5] += xm * wv1.y;
                acc[m][6] += xm * wv1.z; acc[m][7] += xm * wv1.w;
            }
        }
    }

    // z = acc + nub; in-register LayerNorm per row (16 tc-lanes hold a row)
    for (int m = 0; m < 4; m++){
        float z[8];
        float s = 0.0f, ss = 0.0f;
        #pragma unroll
        for (int j = 0; j < 8; j++){
            z[j] = acc[m][j] + nubs[tc * 8 + j];
            s += z[j]; ss += z[j] * z[j];
        }
        s  += __shfl_xor(s, 1);  s  += __shfl_xor(s, 2);
        s  += __shfl_xor(s, 4);  s  += __shfl_xor(s, 8);
        ss += __shfl_xor(ss, 1); ss += __shfl_xor(ss, 2);
        ss += __shfl_xor(ss, 4); ss += __shfl_xor(ss, 8);
        float mean = s * (1.0f / 128.0f);
        float var  = ss * (1.0f / 128.0f) - mean * mean;
        float rstd = rsqrtf(var + 1e-5f);
        int grow = R0 + tr + 16 * m;
        if (grow < NN){
            float4 o0, o1;
            float o[8];
            #pragma unroll
            for (int j = 0; j < 8; j++){
                int col = tc * 8 + j;
                float v = (z[j] - mean) * rstd * lngs[col] + lnbs[col];
                o[j] = v > 0.0f ? v : 0.0f;
            }
            o0.x = o[0]; o0.y = o[1]; o0.z = o[2]; o0.w = o[3];
            o1.x = o[4]; o1.y = o[5]; o1.z = o[6]; o1.w = o[7];
            float* op = out + ((long)et * NN + grow) * DD + tc * 8;
            *(float4*)(op)     = o0;
            *(float4*)(op + 4) = o1;
        }
    }
}

// ---------------------------------------------------------------------------
extern "C" void kernel_launch(void* const* d_in, const int* in_sizes, int n_in,
                              void* d_out, int out_size, void* d_ws, size_t ws_size,
                              hipStream_t stream)
{
    const float* x    = (const float*)d_in[0];
    const int*   ei   = (const int*)d_in[1];
    const float* ea   = (const float*)d_in[2];
    const float* bdW1 = (const float*)d_in[3];
    const float* bdb1 = (const float*)d_in[4];
    const float* bdW2 = (const float*)d_in[5];
    const float* bdb2 = (const float*)d_in[6];
    const float* bdW3 = (const float*)d_in[7];
    const float* bdb3 = (const float*)d_in[8];
    const float* etW1 = (const float*)d_in[9];
    const float* etb1 = (const float*)d_in[10];
    const float* etW2 = (const float*)d_in[11];
    const float* etb2 = (const float*)d_in[12];
    const float* bwW1 = (const float*)d_in[13];
    const float* bwb1 = (const float*)d_in[14];
    const float* bwW2 = (const float*)d_in[15];
    const float* bwb2 = (const float*)d_in[16];
    const float* bwW3 = (const float*)d_in[17];
    const float* bwb3 = (const float*)d_in[18];
    const float* nuW  = (const float*)d_in[19];
    const float* nub  = (const float*)d_in[20];
    const float* lng  = (const float*)d_in[21];
    const float* lnb  = (const float*)d_in[22];

    // workspace layout (bytes):
    //   agg    [2*N*128] f32 : 51,200,000   @ 0
    //     aliased (both dead before k_gather overwrites all of agg):
    //       barr [2*NB*BCAP] uint2 = 16,056,320  @ 0
    //       crec [2*E]       u32   =  6,400,000  @ 17,000,000
    //   tws    [2*N*128] bf16: 25,600,000   @ 51,200,000
    //   bws    [2*N]     f32 :    400,000   @ 76,800,000
    //   deg    [2*N]     i32 :    400,000   @ 77,200,000
    //   bcur   [2*NB]    i32 :      1,568   @ 77,600,000   (zeroed by k_zero)
    //   rowptr [2*N]     i32 :    400,000   @ 77,602,048
    //   epair  [2*E]     u32 :  6,400,000   @ 78,002,048
    //   bsum   [2*25]    i32 :        200   @ 84,402,048
    //   boff   [2*25]    i32 :        200   @ 84,402,560
    char*  wsb    = (char*)d_ws;
    float* agg    = (float*)(wsb);
    uint2* barr   = (uint2*)(wsb);
    unsigned int* crec = (unsigned int*)(wsb + 17000000L);
    u16*   tws    = (u16*)  (wsb + 51200000L);
    float* bws    = (float*)(wsb + 76800000L);
    int*   deg    = (int*)  (wsb + 77200000L);
    int*   bcur   = (int*)  (wsb + 77600000L);
    int*   rowptr = (int*)  (wsb + 77602048L);
    unsigned int* epair = (unsigned int*)(wsb + 78002048L);
    int*   bsum   = (int*)  (wsb + 84402048L);
    int*   boff   = (int*)  (wsb + 84402560L);

    dim3 blk(256);
    // zero bcur only (deg is fully overwritten by k_deg)
    k_zero<<<dim3((2 * NB + 255) / 256), blk, 0, stream>>>(bcur, 2 * NB);

    dim3 g1((NN + 63) / 64, 2);
    k_boundary <<<g1, blk, 0, stream>>>(x, bdW1, bdb1, bdW2, bdb2, bdW3, bdb3, bws);
    k_edgetrans<<<g1, blk, 0, stream>>>(x, etW1, etb1, etW2, etb2, tws);

    dim3 ge(EE / 256, 2);    // 800000/256 = 3125 exactly
    k_coef<<<ge, blk, 0, stream>>>(ei, ea, bwW1, bwb1, bwW2, bwb2, bwW3, bwb3,
                                   bws, crec);

    dim3 gb((EE + 4095) / 4096, 2);   // 196 blocks x 512 threads, 4096 edges each
    k_bucket2<<<gb, dim3(512), 0, stream>>>(ei, crec, bcur, barr);

    dim3 gp(NB, 2);   // one block per (et, bucket)
    k_deg<<<gp, blk, 0, stream>>>(barr, bcur, deg);

    dim3 gs(SCAN_BLK, 2);
    k_scan_local<<<gs, blk, 0, stream>>>(deg, rowptr, bsum);
    k_scan_bsum <<<dim3(1), dim3(64), 0, stream>>>(bsum, boff);
    k_scan_add  <<<gs, blk, 0, stream>>>(rowptr, boff);

    k_sortb<<<gp, blk, 0, stream>>>(barr, bcur, rowptr, epair);

    k_gather<<<dim3(NN / 4, 2), blk, 0, stream>>>(rowptr, deg, epair, tws, agg);

    k_final<<<g1, blk, 0, stream>>>(agg, x, nuW, nub, lng, lnb, (float*)d_out);
}